// Round 3
// baseline (209.986 us; speedup 1.0000x reference)
//
#include <hip/hip_runtime.h>
#include <hip/hip_bf16.h>
#include <math.h>

#define BQ   2      // batch
#define NN   1024   // seq len
#define DMD  512    // d_model
#define NH   8      // heads
#define DKK  64     // head dim
#define NSEL 5      // NB+1 block values (0..4)
#define NCLS 17     // block-pair classes
#define NP   1280   // padded per-batch capacity: nTot = sum(ceil(c_i/64)*64) <= 1339 and %64==0 -> <=1280
#define NPT  20     // NP/64 tiles
#define MAXT 3      // max key-tiles per wave in k_attn (ceil(20/8))
#define SSp  1284   // S row stride (shorts) in fused fallback
#define QLS  68     // qloc/u row stride (shorts)
#define ITPB 80     // it-tiles per (b,h)

typedef __attribute__((ext_vector_type(8))) short bf16x8;
typedef __attribute__((ext_vector_type(8))) unsigned short u16x8;
typedef __attribute__((ext_vector_type(4))) float f32x4;

__device__ __forceinline__ int clsOf(int r, int c) { return (r == 0 || c == 0) ? 0 : ((r - 1) * 4 + c); }

__device__ __forceinline__ unsigned short f2bf(float x) {
    __hip_bfloat16 h = __float2bfloat16(x);
    return *reinterpret_cast<unsigned short*>(&h);
}

// ---------------------------------------------------------------- prep: lin cast (960) + wmix (272) + qkv cast (96) + setup (1)
__global__ __launch_bounds__(256) void k_prep(
    const float* __restrict__ lr, unsigned short* __restrict__ Lt,
    const float* __restrict__ W1, const float* __restrict__ W2,
    const float* __restrict__ al1, const float* __restrict__ al2,
    unsigned short* __restrict__ W1bt, unsigned short* __restrict__ W2bt,
    const float* __restrict__ qr, const float* __restrict__ kr, const float* __restrict__ vr,
    unsigned short* __restrict__ Xc,
    const void* __restrict__ b_seq_r, const void* __restrict__ mask_r,
    int* __restrict__ maskI, int* __restrict__ perm, int* __restrict__ rowc,
    int* __restrict__ startPad, int* __restrict__ maskP)
{
    __shared__ float Tf[64][68];
    __shared__ int det[5];
    __shared__ int cnts[BQ][NSEL];
    __shared__ int offs[BQ][NSEL];
    __shared__ int sstart[BQ][NSEL + 1];
    int bx = blockIdx.x;
    int tid = threadIdx.x;
    if (bx < 960) {
        // cast+transpose lin[ts][k][n] -> Lt[ts][n][k] bf16
        int ts = bx >> 6, rem = bx & 63;
        int kt = rem >> 3, nt = rem & 7;
        const float* src = lr + (size_t)ts * DMD * 512;
        unsigned short* dst = Lt + (size_t)ts * DMD * 512;
        int r = tid >> 2, c4 = tid & 3;
#pragma unroll
        for (int i = 0; i < 4; i++) {
            float4 v = *(const float4*)&src[(size_t)(kt * 64 + r) * 512 + nt * 64 + c4 * 16 + i * 4];
            *(float4*)&Tf[r][c4 * 16 + i * 4] = v;
        }
        __syncthreads();
        unsigned short tmp[16];
#pragma unroll
        for (int i = 0; i < 16; i++) tmp[i] = f2bf(Tf[c4 * 16 + i][r]);
        u16x8 o0, o1;
#pragma unroll
        for (int i = 0; i < 8; i++) { o0[i] = tmp[i]; o1[i] = tmp[8 + i]; }
        unsigned short* dp = &dst[(size_t)(nt * 64 + r) * 512 + kt * 64 + c4 * 16];
        *(u16x8*)&dp[0] = o0;
        *(u16x8*)&dp[8] = o1;
    } else if (bx < 960 + 2 * NCLS * NH) {
        int bid = bx - 960;
        int w = bid / (NCLS * NH);
        int rem = bid % (NCLS * NH);
        int c = rem / NH, h = rem % NH;
        const float* W = w ? W2 : W1;
        const float* a = w ? al2 : al1;
        unsigned short* outp = (w ? W2bt : W1bt) + (((size_t)c * NH + h) << 12);
        float vals[4], mx = -1e30f;
#pragma unroll
        for (int bb = 0; bb < 4; bb++) { vals[bb] = a[(c * 4 + bb) * NH + h]; mx = fmaxf(mx, vals[bb]); }
        float ssum = 0.f;
#pragma unroll
        for (int bb = 0; bb < 4; bb++) { vals[bb] = __expf(vals[bb] - mx); ssum += vals[bb]; }
        float inv = 1.0f / ssum;
        float s0 = vals[0] * inv, s1 = vals[1] * inv, s2 = vals[2] * inv, s3 = vals[3] * inv;
        const float* p0 = W + (size_t)(0 * NH + h) * 4096;
        const float* p1 = W + (size_t)(1 * NH + h) * 4096;
        const float* p2 = W + (size_t)(2 * NH + h) * 4096;
        const float* p3 = W + (size_t)(3 * NH + h) * 4096;
        for (int e = tid; e < 4096; e += 256) {
            float v = s0 * p0[e] + s1 * p1[e] + s2 * p2[e] + s3 * p3[e];
            int mm = e >> 6, nn = e & 63;
            outp[nn * 64 + mm] = f2bf(v);     // transposed store
        }
    } else if (bx < 960 + 2 * NCLS * NH + 96) {
        // cast q/k/v -> Xc bf16 [t][b][n][512]
        int bid = bx - (960 + 2 * NCLS * NH);   // 0..95
        int t = bid / 32, rem = bid % 32;
        int b = rem / 16, rg = rem % 16;
        int row = tid >> 2, part = tid & 3;
        const float* X = (t == 0) ? qr : ((t == 1) ? kr : vr);
        const float* src = X + ((size_t)b * NN + rg * 64 + row) * DMD + part * 128;
        unsigned short* dst = Xc + (((size_t)t * BQ + b) * NN + rg * 64 + row) * DMD + part * 128;
#pragma unroll
        for (int i = 0; i < 128; i += 8) {
            float4 v0 = *(const float4*)&src[i];
            float4 v1 = *(const float4*)&src[i + 4];
            u16x8 o;
            o[0] = f2bf(v0.x); o[1] = f2bf(v0.y); o[2] = f2bf(v0.z); o[3] = f2bf(v0.w);
            o[4] = f2bf(v1.x); o[5] = f2bf(v1.y); o[6] = f2bf(v1.z); o[7] = f2bf(v1.w);
            *(u16x8*)&dst[i] = o;
        }
    } else {
        // ---- setup (single block): dtype detect, bucketize, perm, masks
        if (tid < 5) det[tid] = 0;
        if (tid < BQ * NSEL) { cnts[tid / NSEL][tid % NSEL] = 0; offs[tid / NSEL][tid % NSEL] = 0; }
        __syncthreads();
        const int* b32 = (const int*)b_seq_r;
        const unsigned char* mb = (const unsigned char*)mask_r;
        const int* m32 = (const int*)mask_r;
        if (tid < 64) {
            if (b32[2 * tid + 1] != 0) atomicOr(&det[0], 1);
            if (b32[2 * tid] != 0)     atomicOr(&det[1], 1);
            if (m32[2 * tid + 1] != 0) atomicOr(&det[3], 1);
            if (m32[2 * tid] != 0)     atomicOr(&det[4], 1);
        }
        if ((tid & 3) != 0 && mb[tid] != 0) atomicOr(&det[2], 1);
        __syncthreads();
        int bsI64 = (det[0] == 0 && det[1] != 0);
        int mk = det[2] ? 1 : ((det[3] == 0 && det[4] != 0) ? 2 : 0);

        for (int g = tid; g < BQ * NN; g += 256) {
            int m = (mk == 1) ? (mb[g] != 0) : ((mk == 2) ? (m32[2 * g] != 0) : (m32[g] != 0));
            maskI[g] = m;
            int bs = bsI64 ? b32[2 * g] : b32[g];
            bs = bs < 0 ? 0 : (bs > 4 ? 4 : bs);
            atomicAdd(&cnts[g / NN][bs], 1);
        }
        __syncthreads();
        if (tid == 0) {
            for (int b = 0; b < BQ; b++) {
                int acc = 0;
                for (int c = 0; c < NSEL; c++) {
                    sstart[b][c] = acc;
                    acc += ((cnts[b][c] + 63) / 64) * 64;
                }
                sstart[b][NSEL] = acc;
                for (int c = 0; c <= NSEL; c++) startPad[b * (NSEL + 1) + c] = sstart[b][c];
            }
        }
        __syncthreads();
        for (int g = tid; g < BQ * NP; g += 256) {
            perm[g] = -1;
            int b = g / NP, sslot = g % NP;
            int c = 0;
            for (int cc = 1; cc < NSEL; cc++) if (sslot >= sstart[b][cc]) c = cc;
            rowc[g] = c;
        }
        __syncthreads();
        for (int g = tid; g < BQ * NN; g += 256) {
            int b = g / NN, n = g % NN;
            int bs = bsI64 ? b32[2 * g] : b32[g];
            bs = bs < 0 ? 0 : (bs > 4 ? 4 : bs);
            int pos = sstart[b][bs] + atomicAdd(&offs[b][bs], 1);
            perm[b * NP + pos] = n;
        }
        __syncthreads();
        for (int g = tid; g < BQ * NP; g += 256) {
            int tok = perm[g];
            maskP[g] = (tok < 0) ? 2 : maskI[(g / NP) * NN + tok];
        }
    }
}

// ---------------------------------------------------------------- QKV projection, MFMA bf16, XCD-aligned with k_attn
__global__ __launch_bounds__(256) void k_proj(
    const unsigned short* __restrict__ Xc,
    const unsigned short* __restrict__ Lt,
    const int* __restrict__ perm, const int* __restrict__ rowc, const int* __restrict__ startPad,
    unsigned short* __restrict__ Qb, unsigned short* __restrict__ Kb,
    unsigned short* __restrict__ Vt)
{
    int bid = blockIdx.x;
    int xcd = bid & 7, local = bid >> 3;          // 0..59
    int t = local / NPT, ti = local % NPT;
    int qtr = xcd & 3, b = xcd >> 2;

    int nTot = startPad[b * (NSEL + 1) + NSEL];
    if (ti * 64 >= nTot) return;
    int sel = rowc[b * NP + ti * 64];
    const unsigned short* XcT = Xc + ((size_t)t * BQ + b) * NN * DMD;
    const unsigned short* L = Lt + (size_t)(t * NSEL + sel) * DMD * 512;   // [n][k] bf16

    __shared__ __align__(16) unsigned short Xb[64][72];
    __shared__ __align__(16) unsigned short Lb[128][72];
    __shared__ int toks[64];

    int tid = threadIdx.x;
    int wave = tid >> 6, lane = tid & 63;
    int m = lane & 15, q = lane >> 4;
    if (tid < 64) toks[tid] = perm[b * NP + ti * 64 + tid];
    __syncthreads();

    int xr = tid >> 2, xc0 = (tid & 3) * 16;
    int xtok = toks[xr];
    const unsigned short* xbase = (xtok >= 0) ? &XcT[(size_t)xtok * DMD] : (const unsigned short*)0;
    int ln = tid >> 1, lhf = tid & 1;
    const unsigned short* lbase = &L[(size_t)(qtr * 128 + ln) * 512 + lhf * 32];

    u16x8 rx0 = {0, 0, 0, 0, 0, 0, 0, 0}, rx1 = {0, 0, 0, 0, 0, 0, 0, 0};
    u16x8 rl0, rl1, rl2, rl3;
    if (xbase) { rx0 = *(const u16x8*)&xbase[xc0]; rx1 = *(const u16x8*)&xbase[xc0 + 8]; }
    rl0 = *(const u16x8*)&lbase[0];  rl1 = *(const u16x8*)&lbase[8];
    rl2 = *(const u16x8*)&lbase[16]; rl3 = *(const u16x8*)&lbase[24];

    f32x4 acc[4][2];
#pragma unroll
    for (int mt = 0; mt < 4; mt++) { acc[mt][0] = {0, 0, 0, 0}; acc[mt][1] = {0, 0, 0, 0}; }

    for (int kb = 0; kb < DMD; kb += 64) {
        *(u16x8*)&Xb[xr][xc0] = rx0;
        *(u16x8*)&Xb[xr][xc0 + 8] = rx1;
        *(u16x8*)&Lb[ln][lhf * 32 + 0]  = rl0;
        *(u16x8*)&Lb[ln][lhf * 32 + 8]  = rl1;
        *(u16x8*)&Lb[ln][lhf * 32 + 16] = rl2;
        *(u16x8*)&Lb[ln][lhf * 32 + 24] = rl3;
        __syncthreads();
        if (kb + 64 < DMD) {   // prefetch next slab (overlaps MFMAs)
            int nk = kb + 64;
            if (xbase) { rx0 = *(const u16x8*)&xbase[nk + xc0]; rx1 = *(const u16x8*)&xbase[nk + xc0 + 8]; }
            rl0 = *(const u16x8*)&lbase[nk];      rl1 = *(const u16x8*)&lbase[nk + 8];
            rl2 = *(const u16x8*)&lbase[nk + 16]; rl3 = *(const u16x8*)&lbase[nk + 24];
        }
#pragma unroll
        for (int kc = 0; kc < 64; kc += 32) {
            bf16x8 bf0 = *(const bf16x8*)&Lb[wave * 32 + m][kc + q * 8];
            bf16x8 bf1 = *(const bf16x8*)&Lb[wave * 32 + 16 + m][kc + q * 8];
#pragma unroll
            for (int mt = 0; mt < 4; mt++) {
                bf16x8 a = *(const bf16x8*)&Xb[mt * 16 + m][kc + q * 8];
                acc[mt][0] = __builtin_amdgcn_mfma_f32_16x16x32_bf16(a, bf0, acc[mt][0], 0, 0, 0);
                acc[mt][1] = __builtin_amdgcn_mfma_f32_16x16x32_bf16(a, bf1, acc[mt][1], 0, 0, 0);
            }
        }
        __syncthreads();
    }

    if (t < 2) {
        unsigned short* O = (t == 0) ? Qb : Kb;
#pragma unroll
        for (int mt = 0; mt < 4; mt++)
#pragma unroll
            for (int nt = 0; nt < 2; nt++)
#pragma unroll
                for (int gg = 0; gg < 4; gg++) {
                    int i = mt * 16 + q * 4 + gg;
                    int hk = qtr * 128 + wave * 32 + nt * 16 + m;
                    int h = hk >> 6, k0 = hk & 63;
                    O[(((size_t)b * NH + h) * NP + ti * 64 + i) * 64 + k0] = f2bf(acc[mt][nt][gg]);
                }
    } else {
        // transpose via Lb (dead), write Vt[b][h][d][ip] coalesced
#pragma unroll
        for (int mt = 0; mt < 4; mt++)
#pragma unroll
            for (int nt = 0; nt < 2; nt++)
#pragma unroll
                for (int gg = 0; gg < 4; gg++)
                    Lb[wave * 32 + nt * 16 + m][mt * 16 + q * 4 + gg] = f2bf(acc[mt][nt][gg]);
        __syncthreads();
        int hkl = tid >> 1, hf = tid & 1;
        int hk = qtr * 128 + hkl;
        int h = hk >> 6, d = hk & 63;
        unsigned short* vp = Vt + (((size_t)b * NH + h) * DKK + d) * NP + ti * 64 + hf * 32;
#pragma unroll
        for (int s = 0; s < 4; s++)
            *(u16x8*)&vp[s * 8] = *(const u16x8*)&Lb[hkl][hf * 32 + s * 8];
    }
}

// ---------------------------------------------------------------- split attention, part 1: Q·W1, scores, softmax -> Sg (global) + wsumG
// LDS 12 KB, VGPR ~56 -> 4 blocks/CU (32 waves, wave-slot cap). No phase-3/4 coupling.
__global__ __launch_bounds__(512, 4) void k_attn1(
    const unsigned short* __restrict__ Qb, const unsigned short* __restrict__ Kb,
    const unsigned short* __restrict__ W1bt,
    const int* __restrict__ perm, const int* __restrict__ rowc, const int* __restrict__ startPad,
    const int* __restrict__ maskI, const int* __restrict__ maskP,
    unsigned short* __restrict__ Sg, float* __restrict__ wsumG)
{
    int bid = blockIdx.x;
    int xcd = bid & 7, local = bid >> 3;          // 0..159
    int bh = xcd * 2 + (local >= ITPB ? 1 : 0);
    int it = (local >= ITPB) ? (local - ITPB) : local;
    int b = bh >> 3, h = bh & 7;
    int nTot = startPad[b * (NSEL + 1) + NSEL];
    int i0 = it * 16;
    if (i0 >= nTot) return;
    int r = rowc[b * NP + i0];
    int tiles = nTot >> 6;

    __shared__ __align__(16) unsigned short qloc[NSEL][16][QLS];
    __shared__ float wred[8][16];
    __shared__ float wsum[8][16];
    __shared__ int tilec[NPT];
    __shared__ int mrow[16];

    int tid = threadIdx.x;
    int wave = tid >> 6, lane = tid & 63;
    int m = lane & 15, q = lane >> 4;

    const int* permB = perm + b * NP;
    const unsigned short* QbB = Qb + (size_t)bh * NP * 64;
    const unsigned short* KbB = Kb + (size_t)bh * NP * 64;
    const int* maskPB = maskP + b * NP;
    unsigned short* SgB = Sg + (size_t)(bh * ITPB + it) * 16 * NP;

    if (tid < NPT) tilec[tid] = rowc[b * NP + tid * 64];
    else if (tid >= 64 && tid < 80) {
        int rr = tid - 64;
        int tok = permB[i0 + rr];
        mrow[rr] = (tok >= 0) ? maskI[b * NN + tok] : 0;
    }

    // ---- phase 0b: qloc[c][i][n] = Q . W1m[cls(r,c)]
    {
        const unsigned short* qa = &QbB[(size_t)(i0 + m) * 64 + q * 8];
        bf16x8 a0 = *(const bf16x8*)qa;
        bf16x8 a1 = *(const bf16x8*)(qa + 32);
        int sub = wave & 3;
        int c0 = (wave >> 2) ? 3 : 0;
        int c1 = (wave >> 2) ? 5 : 3;
        for (int c = c0; c < c1; c++) {
            int cls = clsOf(r, c);
            const unsigned short* wb = W1bt + (((size_t)cls * NH + h) << 12)
                                     + (size_t)(sub * 16 + m) * 64 + q * 8;
            bf16x8 b0 = *(const bf16x8*)wb;
            bf16x8 b1 = *(const bf16x8*)(wb + 32);
            f32x4 acc = {0.f, 0.f, 0.f, 0.f};
            acc = __builtin_amdgcn_mfma_f32_16x16x32_bf16(a0, b0, acc, 0, 0, 0);
            acc = __builtin_amdgcn_mfma_f32_16x16x32_bf16(a1, b1, acc, 0, 0, 0);
#pragma unroll
            for (int g = 0; g < 4; g++)
                qloc[c][q * 4 + g][sub * 16 + m] = f2bf(acc[g]);
        }
    }
    __syncthreads();

    // ---- phase 1: scores in registers
    float sarr[MAXT][4][4];
    float lmax[4] = {-INFINITY, -INFINITY, -INFINITY, -INFINITY};
    int mrow4[4];
#pragma unroll
    for (int g = 0; g < 4; g++) mrow4[g] = mrow[q * 4 + g];

#pragma unroll
    for (int tt = 0; tt < MAXT; tt++) {
        int jt = wave + tt * 8;
        bool valid = (jt < tiles);
        int jts = valid ? jt : 0;
        int c = tilec[jts];
        int jb = jts * 64;
        const unsigned short* qa = &qloc[c][m][q * 8];
        bf16x8 a0 = *(const bf16x8*)qa;
        bf16x8 a1 = *(const bf16x8*)(qa + 32);
        bf16x8 kreg[8];
        int mj4[4];
#pragma unroll
        for (int nb = 0; nb < 4; nb++) {
            int j = jb + nb * 16 + m;
            const unsigned short* kb = &KbB[(size_t)j * 64 + q * 8];
            kreg[nb * 2]     = *(const bf16x8*)kb;
            kreg[nb * 2 + 1] = *(const bf16x8*)(kb + 32);
            mj4[nb] = maskPB[j];
        }
#pragma unroll
        for (int nb = 0; nb < 4; nb++) {
            f32x4 acc = {0.f, 0.f, 0.f, 0.f};
            acc = __builtin_amdgcn_mfma_f32_16x16x32_bf16(a0, kreg[nb * 2], acc, 0, 0, 0);
            acc = __builtin_amdgcn_mfma_f32_16x16x32_bf16(a1, kreg[nb * 2 + 1], acc, 0, 0, 0);
            int mj = mj4[nb];
#pragma unroll
            for (int g = 0; g < 4; g++) {
                float sv;
                if (!valid || mj == 2)   sv = -INFINITY;      // padding / no tile
                else if (mrow4[g] && mj) sv = acc[g] * 0.125f;
                else                     sv = -1e30f;         // reference's masked value
                sarr[tt][nb][g] = sv;
                lmax[g] = fmaxf(lmax[g], sv);
            }
        }
    }
#pragma unroll
    for (int g = 0; g < 4; g++) {
        float v = lmax[g];
#pragma unroll
        for (int o = 1; o < 16; o <<= 1) v = fmaxf(v, __shfl_xor(v, o));
        lmax[g] = v;
    }
    if (m == 0) {
#pragma unroll
        for (int g = 0; g < 4; g++) wred[wave][q * 4 + g] = lmax[g];
    }
    __syncthreads();

    // ---- phase 2: exp in regs, write P to global Sg, row sums
    float mx4[4], lsum[4] = {0.f, 0.f, 0.f, 0.f};
#pragma unroll
    for (int g = 0; g < 4; g++) {
        int i = q * 4 + g;
        float v = wred[0][i];
#pragma unroll
        for (int w2 = 1; w2 < 8; w2++) v = fmaxf(v, wred[w2][i]);
        mx4[g] = v;
    }
#pragma unroll
    for (int tt = 0; tt < MAXT; tt++) {
        int jt = wave + tt * 8;
        bool valid = (jt < tiles);
        int jb = jt * 64;
#pragma unroll
        for (int nb = 0; nb < 4; nb++) {
            int j = jb + nb * 16 + m;
#pragma unroll
            for (int g = 0; g < 4; g++) {
                float p = __expf(sarr[tt][nb][g] - mx4[g]);   // -inf -> 0
                lsum[g] += p;
                if (valid) SgB[(size_t)(q * 4 + g) * NP + j] = f2bf(p);
            }
        }
    }
#pragma unroll
    for (int g = 0; g < 4; g++) {
        float v = lsum[g];
#pragma unroll
        for (int o = 1; o < 16; o <<= 1) v += __shfl_xor(v, o);
        lsum[g] = v;
    }
    if (m == 0) {
#pragma unroll
        for (int g = 0; g < 4; g++) wsum[wave][q * 4 + g] = lsum[g];
    }
    __syncthreads();

    if (tid < 16) {
        float s = wsum[0][tid] + wsum[1][tid] + wsum[2][tid] + wsum[3][tid]
                + wsum[4][tid] + wsum[5][tid] + wsum[6][tid] + wsum[7][tid];
        wsumG[(size_t)(bh * ITPB + it) * 16 + tid] = s;
    }
}

// ---------------------------------------------------------------- split attention, part 2: per-class PV -> u, u·W2 -> out
// LDS 19 KB -> 4 blocks/CU (wave-slot cap). Only 3 barriers.
__global__ __launch_bounds__(512, 4) void k_attn2(
    const unsigned short* __restrict__ Vt, const unsigned short* __restrict__ W2bt,
    const int* __restrict__ perm, const int* __restrict__ rowc, const int* __restrict__ startPad,
    const unsigned short* __restrict__ Sg, const float* __restrict__ wsumG,
    float* __restrict__ out)
{
    int bid = blockIdx.x;
    int xcd = bid & 7, local = bid >> 3;          // 0..159
    int bh = xcd * 2 + (local >= ITPB ? 1 : 0);
    int it = (local >= ITPB) ? (local - ITPB) : local;
    int b = bh >> 3, h = bh & 7;
    int nTot = startPad[b * (NSEL + 1) + NSEL];
    int i0 = it * 16;
    if (i0 >= nTot) return;
    int r = rowc[b * NP + i0];

    __shared__ __align__(16) unsigned short u[NSEL][16][QLS];
    __shared__ float pbuf[2][16][64];
    __shared__ int cstart[6];
    __shared__ int toki[16];

    int tid = threadIdx.x;
    int wave = tid >> 6, lane = tid & 63;
    int m = lane & 15, q = lane >> 4;

    const unsigned short* VtB = Vt + (size_t)bh * DKK * NP;      // [d][jp]
    const unsigned short* SgB = Sg + (size_t)(bh * ITPB + it) * 16 * NP;

    if (tid < 6) cstart[tid] = startPad[b * (NSEL + 1) + tid];
    else if (tid >= 64 && tid < 80) toki[tid - 64] = perm[b * NP + i0 + (tid - 64)];
    __syncthreads();

    // ---- phase 3: per-class PV into u; dynamic split + 1-deep prefetch
    {
        int kw = wave & 3, chalf = wave >> 2;
        int db = kw * 16;
        int nT2 = cstart[5];
        int sc = 1, best = 0x7fffffff;
#pragma unroll
        for (int c = 1; c <= 4; c++) {
            int d = 2 * cstart[c] - nT2;
            d = d < 0 ? -d : d;
            if (d < best) { best = d; sc = c; }
        }
        int cb = chalf ? sc : 0, ce = chalf ? 5 : sc;
        int t0 = cstart[cb] >> 6, tEnd = cstart[ce] >> 6;
        const unsigned short* Srow = &SgB[(size_t)m * NP + q * 8];
        const unsigned short* Vrow = &VtB[(size_t)(db + m) * NP + q * 8];
        bf16x8 a0 = {}, a1 = {}, b0 = {}, b1 = {};
        if (t0 < tEnd) {
            int jb = t0 * 64;
            a0 = *(const bf16x8*)&Srow[jb];  a1 = *(const bf16x8*)&Srow[jb + 32];
            b0 = *(const bf16x8*)&Vrow[jb];  b1 = *(const bf16x8*)&Vrow[jb + 32];
        }
        int tcur = t0;
        for (int c = cb; c < ce; c++) {
            int ct1 = cstart[c + 1] >> 6;
            f32x4 ae = {0.f, 0.f, 0.f, 0.f};
            f32x4 ao = {0.f, 0.f, 0.f, 0.f};
            while (tcur < ct1) {
                bf16x8 ca0 = a0, ca1 = a1, cb0 = b0, cb1 = b1;
                int tn = tcur + 1;
                if (tn < tEnd) {             // prefetch next tile (crosses class boundary)
                    int jb = tn * 64;
                    a0 = *(const bf16x8*)&Srow[jb];  a1 = *(const bf16x8*)&Srow[jb + 32];
                    b0 = *(const bf16x8*)&Vrow[jb];  b1 = *(const bf16x8*)&Vrow[jb + 32];
                }
                ae = __builtin_amdgcn_mfma_f32_16x16x32_bf16(ca0, cb0, ae, 0, 0, 0);
                ao = __builtin_amdgcn_mfma_f32_16x16x32_bf16(ca1, cb1, ao, 0, 0, 0);
                tcur++;
            }
#pragma unroll
            for (int g = 0; g < 4; g++)
                u[c][q * 4 + g][db + m] = f2bf(ae[g] + ao[g]);
        }
    }
    __syncthreads();

    // ---- phase 4: out = (sum_c u[c] . W2m[cls(r,c)])
    {
        int kw = wave & 3, p = wave >> 2;
        int cb = p ? 3 : 0, ce = p ? 5 : 3;
        f32x4 acc = {0.f, 0.f, 0.f, 0.f};
        for (int c = cb; c < ce; c++) {
            int cls = clsOf(r, c);
            const unsigned short* ua = &u[c][m][q * 8];
            bf16x8 a0 = *(const bf16x8*)ua;
            bf16x8 a1 = *(const bf16x8*)(ua + 32);
            const unsigned short* wb = W2bt + (((size_t)cls * NH + h) << 12)
                                     + (size_t)(kw * 16 + m) * 64 + q * 8;
            bf16x8 b0 = *(const bf16x8*)wb;
            bf16x8 b1 = *(const bf16x8*)(wb + 32);
            acc = __builtin_amdgcn_mfma_f32_16x16x32_bf16(a0, b0, acc, 0, 0, 0);
            acc = __builtin_amdgcn_mfma_f32_16x16x32_bf16(a1, b1, acc, 0, 0, 0);
        }
#pragma unroll
        for (int g = 0; g < 4; g++)
            pbuf[p][q * 4 + g][kw * 16 + m] = acc[g];
    }
    __syncthreads();

    // ---- epilogue: combine halves, normalize, store
    const float* wsB = wsumG + (size_t)(bh * ITPB + it) * 16;
    for (int idx = tid; idx < 16 * 64; idx += 512) {
        int i = idx >> 6, k = idx & 63;
        int tok = toki[i];
        if (tok >= 0) {
            float v = pbuf[0][i][k] + pbuf[1][i][k];
            out[((size_t)b * NN + tok) * (NH * DKK) + h * DKK + k] = v / wsB[i];
        }
    }
}

// ---------------------------------------------------------------- fused attention fallback (workspace too small for Sg)
__global__ __launch_bounds__(512, 4) void k_attn(
    const unsigned short* __restrict__ Qb, const unsigned short* __restrict__ Kb,
    const unsigned short* __restrict__ Vt, const unsigned short* __restrict__ W1bt,
    const unsigned short* __restrict__ W2bt,
    const int* __restrict__ perm, const int* __restrict__ rowc, const int* __restrict__ startPad,
    const int* __restrict__ maskI, const int* __restrict__ maskP,
    float* __restrict__ out)
{
    int bid = blockIdx.x;
    int xcd = bid & 7, local = bid >> 3;          // 0..159
    int bh = xcd * 2 + (local >= 80 ? 1 : 0);
    int it = (local >= 80) ? (local - 80) : local;
    int b = bh >> 3, h = bh & 7;
    int nTot = startPad[b * (NSEL + 1) + NSEL];
    int i0 = it * 16;
    if (i0 >= nTot) return;
    int r = rowc[b * NP + i0];
    int tiles = nTot >> 6;

    __shared__ __align__(16) char smem[16 * SSp * 2 + NSEL * 16 * QLS * 2 + 1024 + 4 * (NPT + 6 + 16 + 16)];
    unsigned short (*S)[SSp] = (unsigned short (*)[SSp])smem;
    unsigned short (*qloc)[16][QLS] = (unsigned short (*)[16][QLS])smem;
    float (*pbuf)[16][64] = (float (*)[16][64])smem;
    unsigned short (*u)[16][QLS] = (unsigned short (*)[16][QLS])(smem + 16 * SSp * 2);
    char* tail = smem + 16 * SSp * 2 + NSEL * 16 * QLS * 2;
    float (*wred)[16] = (float (*)[16])tail;
    float (*wsum)[16] = (float (*)[16])(tail + 512);
    int* tilec = (int*)(tail + 1024);
    int* cstart = tilec + NPT;
    int* mrow = cstart + 6;
    int* toki = mrow + 16;

    int tid = threadIdx.x;
    int wave = tid >> 6, lane = tid & 63;
    int m = lane & 15, q = lane >> 4;

    const int* permB = perm + b * NP;
    const unsigned short* QbB = Qb + (size_t)bh * NP * 64;
    const unsigned short* KbB = Kb + (size_t)bh * NP * 64;
    const unsigned short* VtB = Vt + (size_t)bh * DKK * NP;
    const int* maskPB = maskP + b * NP;

    if (tid < NPT) tilec[tid] = rowc[b * NP + tid * 64];
    else if (tid >= 32 && tid < 38) cstart[tid - 32] = startPad[b * (NSEL + 1) + (tid - 32)];
    else if (tid >= 64 && tid < 80) {
        int rr = tid - 64;
        int tok = permB[i0 + rr];
        toki[rr] = tok;
        mrow[rr] = (tok >= 0) ? maskI[b * NN + tok] : 0;
    }

    {
        const unsigned short* qa = &QbB[(size_t)(i0 + m) * 64 + q * 8];
        bf16x8 a0 = *(const bf16x8*)qa;
        bf16x8 a1 = *(const bf16x8*)(qa + 32);
        int sub = wave & 3;
        int c0 = (wave >> 2) ? 3 : 0;
        int c1 = (wave >> 2) ? 5 : 3;
        for (int c = c0; c < c1; c++) {
            int cls = clsOf(r, c);
            const unsigned short* wb = W1bt + (((size_t)cls * NH + h) << 12)
                                     + (size_t)(sub * 16 + m) * 64 + q * 8;
            bf16x8 b0 = *(const bf16x8*)wb;
            bf16x8 b1 = *(const bf16x8*)(wb + 32);
            f32x4 acc = {0.f, 0.f, 0.f, 0.f};
            acc = __builtin_amdgcn_mfma_f32_16x16x32_bf16(a0, b0, acc, 0, 0, 0);
            acc = __builtin_amdgcn_mfma_f32_16x16x32_bf16(a1, b1, acc, 0, 0, 0);
#pragma unroll
            for (int g = 0; g < 4; g++)
                qloc[c][q * 4 + g][sub * 16 + m] = f2bf(acc[g]);
        }
    }
    __syncthreads();

    float sarr[MAXT][4][4];
    float lmax[4] = {-INFINITY, -INFINITY, -INFINITY, -INFINITY};
    int mrow4[4];
#pragma unroll
    for (int g = 0; g < 4; g++) mrow4[g] = mrow[q * 4 + g];

#pragma unroll
    for (int tt = 0; tt < MAXT; tt++) {
        int jt = wave + tt * 8;
        bool valid = (jt < tiles);
        int jts = valid ? jt : 0;
        int c = tilec[jts];
        int jb = jts * 64;
        const unsigned short* qa = &qloc[c][m][q * 8];
        bf16x8 a0 = *(const bf16x8*)qa;
        bf16x8 a1 = *(const bf16x8*)(qa + 32);
        bf16x8 kreg[8];
        int mj4[4];
#pragma unroll
        for (int nb = 0; nb < 4; nb++) {
            int j = jb + nb * 16 + m;
            const unsigned short* kb = &KbB[(size_t)j * 64 + q * 8];
            kreg[nb * 2]     = *(const bf16x8*)kb;
            kreg[nb * 2 + 1] = *(const bf16x8*)(kb + 32);
            mj4[nb] = maskPB[j];
        }
#pragma unroll
        for (int nb = 0; nb < 4; nb++) {
            f32x4 acc = {0.f, 0.f, 0.f, 0.f};
            acc = __builtin_amdgcn_mfma_f32_16x16x32_bf16(a0, kreg[nb * 2], acc, 0, 0, 0);
            acc = __builtin_amdgcn_mfma_f32_16x16x32_bf16(a1, kreg[nb * 2 + 1], acc, 0, 0, 0);
            int mj = mj4[nb];
#pragma unroll
            for (int g = 0; g < 4; g++) {
                float sv;
                if (!valid || mj == 2)   sv = -INFINITY;
                else if (mrow4[g] && mj) sv = acc[g] * 0.125f;
                else                     sv = -1e30f;
                sarr[tt][nb][g] = sv;
                lmax[g] = fmaxf(lmax[g], sv);
            }
        }
    }
#pragma unroll
    for (int g = 0; g < 4; g++) {
        float v = lmax[g];
#pragma unroll
        for (int o = 1; o < 16; o <<= 1) v = fmaxf(v, __shfl_xor(v, o));
        lmax[g] = v;
    }
    if (m == 0) {
#pragma unroll
        for (int g = 0; g < 4; g++) wred[wave][q * 4 + g] = lmax[g];
    }
    __syncthreads();

    float mx4[4], lsum[4] = {0.f, 0.f, 0.f, 0.f};
#pragma unroll
    for (int g = 0; g < 4; g++) {
        int i = q * 4 + g;
        float v = wred[0][i];
#pragma unroll
        for (int w2 = 1; w2 < 8; w2++) v = fmaxf(v, wred[w2][i]);
        mx4[g] = v;
    }
#pragma unroll
    for (int tt = 0; tt < MAXT; tt++) {
        int jt = wave + tt * 8;
        bool valid = (jt < tiles);
        int jb = jt * 64;
#pragma unroll
        for (int nb = 0; nb < 4; nb++) {
            int j = jb + nb * 16 + m;
#pragma unroll
            for (int g = 0; g < 4; g++) {
                float p = __expf(sarr[tt][nb][g] - mx4[g]);
                lsum[g] += p;
                if (valid) S[q * 4 + g][j] = f2bf(p);
            }
        }
    }
#pragma unroll
    for (int g = 0; g < 4; g++) {
        float v = lsum[g];
#pragma unroll
        for (int o = 1; o < 16; o <<= 1) v += __shfl_xor(v, o);
        lsum[g] = v;
    }
    if (m == 0) {
#pragma unroll
        for (int g = 0; g < 4; g++) wsum[wave][q * 4 + g] = lsum[g];
    }
    __syncthreads();

    {
        int kw = wave & 3, chalf = wave >> 2;
        int db = kw * 16;
        int nT2 = cstart[5];
        int sc = 1, best = 0x7fffffff;
#pragma unroll
        for (int c = 1; c <= 4; c++) {
            int d = 2 * cstart[c] - nT2;
            d = d < 0 ? -d : d;
            if (d < best) { best = d; sc = c; }
        }
        int cb = chalf ? sc : 0, ce = chalf ? 5 : sc;
        int t0 = cstart[cb] >> 6, tEnd = cstart[ce] >> 6;
        const unsigned short* Srow = &S[m][q * 8];
        const unsigned short* Vrow = &VtB[(size_t)(db + m) * NP + q * 8];
        bf16x8 a0 = {}, a1 = {}, b0 = {}, b1 = {};
        if (t0 < tEnd) {
            int jb = t0 * 64;
            a0 = *(const bf16x8*)&Srow[jb];  a1 = *(const bf16x8*)&Srow[jb + 32];
            b0 = *(const bf16x8*)&Vrow[jb];  b1 = *(const bf16x8*)&Vrow[jb + 32];
        }
        int tcur = t0;
        for (int c = cb; c < ce; c++) {
            int ct1 = cstart[c + 1] >> 6;
            f32x4 ae = {0.f, 0.f, 0.f, 0.f};
            f32x4 ao = {0.f, 0.f, 0.f, 0.f};
            while (tcur < ct1) {
                bf16x8 ca0 = a0, ca1 = a1, cb0 = b0, cb1 = b1;
                int tn = tcur + 1;
                if (tn < tEnd) {
                    int jb = tn * 64;
                    a0 = *(const bf16x8*)&Srow[jb];  a1 = *(const bf16x8*)&Srow[jb + 32];
                    b0 = *(const bf16x8*)&Vrow[jb];  b1 = *(const bf16x8*)&Vrow[jb + 32];
                }
                ae = __builtin_amdgcn_mfma_f32_16x16x32_bf16(ca0, cb0, ae, 0, 0, 0);
                ao = __builtin_amdgcn_mfma_f32_16x16x32_bf16(ca1, cb1, ao, 0, 0, 0);
                tcur++;
            }
#pragma unroll
            for (int g = 0; g < 4; g++)
                u[c][q * 4 + g][db + m] = f2bf(ae[g] + ao[g]);
        }
    }
    __syncthreads();

    {
        int kw = wave & 3, p = wave >> 2;
        int cb = p ? 3 : 0, ce = p ? 5 : 3;
        f32x4 acc = {0.f, 0.f, 0.f, 0.f};
        for (int c = cb; c < ce; c++) {
            int cls = clsOf(r, c);
            const unsigned short* ua = &u[c][m][q * 8];
            bf16x8 a0 = *(const bf16x8*)ua;
            bf16x8 a1 = *(const bf16x8*)(ua + 32);
            const unsigned short* wb = W2bt + (((size_t)cls * NH + h) << 12)
                                     + (size_t)(kw * 16 + m) * 64 + q * 8;
            bf16x8 b0 = *(const bf16x8*)wb;
            bf16x8 b1 = *(const bf16x8*)(wb + 32);
            acc = __builtin_amdgcn_mfma_f32_16x16x32_bf16(a0, b0, acc, 0, 0, 0);
            acc = __builtin_amdgcn_mfma_f32_16x16x32_bf16(a1, b1, acc, 0, 0, 0);
        }
#pragma unroll
        for (int g = 0; g < 4; g++)
            pbuf[p][q * 4 + g][kw * 16 + m] = acc[g];
    }
    __syncthreads();

    for (int idx = tid; idx < 16 * 64; idx += 512) {
        int i = idx >> 6, k = idx & 63;
        int tok = toki[i];
        if (tok >= 0) {
            float s = wsum[0][i] + wsum[1][i] + wsum[2][i] + wsum[3][i]
                    + wsum[4][i] + wsum[5][i] + wsum[6][i] + wsum[7][i];
            float v = pbuf[0][i][k] + pbuf[1][i][k];
            out[((size_t)b * NN + tok) * (NH * DKK) + h * DKK + k] = v / s;
        }
    }
}

// ---------------------------------------------------------------- launch
extern "C" void kernel_launch(void* const* d_in, const int* in_sizes, int n_in,
                              void* d_out, int out_size, void* d_ws, size_t ws_size,
                              hipStream_t stream)
{
    const float* qr  = (const float*)d_in[0];
    const float* kr  = (const float*)d_in[1];
    const float* vr  = (const float*)d_in[2];
    const void* bsr  = d_in[3];
    const void* mkr  = d_in[4];
    const float* lr  = (const float*)d_in[5];
    const float* w1r = (const float*)d_in[6];
    const float* a1r = (const float*)d_in[7];
    const float* w2r = (const float*)d_in[8];
    const float* a2r = (const float*)d_in[9];
    float* out = (float*)d_out;

    char* w = (char*)d_ws;
    int* maskI    = (int*)w;
    int* perm     = maskI + BQ * NN;
    int* rowc     = perm + BQ * NP;
    int* startPad = rowc + BQ * NP;
    int* maskP    = startPad + 12;
    unsigned short* W1bt = (unsigned short*)(w + 65536);
    unsigned short* W2bt = W1bt + (size_t)NCLS * NH * 4096;
    unsigned short* Qb   = (unsigned short*)(w + 2359296);
    unsigned short* Kb   = Qb + (size_t)BQ * NH * NP * 64;
    unsigned short* Vt   = Kb + (size_t)BQ * NH * NP * 64;           // [b][h][d][ip]
    unsigned short* Lt   = (unsigned short*)(w + 10616832);
    unsigned short* Xc   = (unsigned short*)(w + 26345472);          // ends at 32,636,928

    const size_t SG_OFF   = 32636928ULL;
    const size_t SG_BYTES = (size_t)BQ * NH * ITPB * 16 * NP * 2;    // 52,428,800
    const size_t WS_OFF   = SG_OFF + SG_BYTES;
    const size_t WS_BYTES = (size_t)BQ * NH * ITPB * 16 * 4;         // 81,920
    unsigned short* Sg    = (unsigned short*)(w + SG_OFF);
    float* wsumG          = (float*)(w + WS_OFF);

    hipLaunchKernelGGL(k_prep, dim3(960 + 2 * NCLS * NH + 96 + 1), dim3(256), 0, stream,
                       lr, Lt, w1r, w2r, a1r, a2r, W1bt, W2bt, qr, kr, vr, Xc,
                       bsr, mkr, maskI, perm, rowc, startPad, maskP);
    hipLaunchKernelGGL(k_proj, dim3(8 * 3 * NPT), dim3(256), 0, stream,
                       Xc, Lt, perm, rowc, startPad, Qb, Kb, Vt);
    if (ws_size >= WS_OFF + WS_BYTES) {
        hipLaunchKernelGGL(k_attn1, dim3(8 * 2 * ITPB), dim3(512), 0, stream,
                           Qb, Kb, W1bt, perm, rowc, startPad, maskI, maskP, Sg, wsumG);
        hipLaunchKernelGGL(k_attn2, dim3(8 * 2 * ITPB), dim3(512), 0, stream,
                           Vt, W2bt, perm, rowc, startPad, Sg, wsumG, out);
    } else {
        hipLaunchKernelGGL(k_attn, dim3(8 * 2 * ITPB), dim3(512), 0, stream,
                           Qb, Kb, Vt, W1bt, W2bt, perm, rowc, startPad, maskI, maskP, out);
    }
}

// Round 4
// 196.457 us; speedup vs baseline: 1.0689x; 1.0689x over previous
//
#include <hip/hip_runtime.h>
#include <hip/hip_bf16.h>
#include <math.h>

#define BQ   2      // batch
#define NN   1024   // seq len
#define DMD  512    // d_model
#define NH   8      // heads
#define DKK  64     // head dim
#define NSEL 5      // NB+1 block values (0..4)
#define NCLS 17     // block-pair classes
#define NP   1280   // padded per-batch capacity: nTot = sum(ceil(c_i/64)*64) <= 1339 and %64==0 -> <=1280
#define NPT  20     // NP/64 tiles
#define MAXT 3      // max key-tiles per wave in k_attn (ceil(20/8))
#define SSp  1284   // S row stride (shorts): 2568B = 642 words == 2 mod 32 banks, conflict-free shift
#define QLS  68     // qloc/u row stride (shorts)

typedef __attribute__((ext_vector_type(8))) short bf16x8;
typedef __attribute__((ext_vector_type(8))) unsigned short u16x8;
typedef __attribute__((ext_vector_type(4))) float f32x4;

__device__ __forceinline__ int clsOf(int r, int c) { return (r == 0 || c == 0) ? 0 : ((r - 1) * 4 + c); }

__device__ __forceinline__ unsigned short f2bf(float x) {
    __hip_bfloat16 h = __float2bfloat16(x);
    return *reinterpret_cast<unsigned short*>(&h);
}

// ---------------------------------------------------------------- prep: lin cast (960) + wmix (272) + qkv cast (96) + setup (1)
__global__ __launch_bounds__(256) void k_prep(
    const float* __restrict__ lr, unsigned short* __restrict__ Lt,
    const float* __restrict__ W1, const float* __restrict__ W2,
    const float* __restrict__ al1, const float* __restrict__ al2,
    unsigned short* __restrict__ W1bt, unsigned short* __restrict__ W2bt,
    const float* __restrict__ qr, const float* __restrict__ kr, const float* __restrict__ vr,
    unsigned short* __restrict__ Xc,
    const void* __restrict__ b_seq_r, const void* __restrict__ mask_r,
    int* __restrict__ maskI, int* __restrict__ perm, int* __restrict__ rowc,
    int* __restrict__ startPad, int* __restrict__ maskP)
{
    __shared__ float Tf[64][68];
    __shared__ int det[5];
    __shared__ int cnts[BQ][NSEL];
    __shared__ int offs[BQ][NSEL];
    __shared__ int sstart[BQ][NSEL + 1];
    int bx = blockIdx.x;
    int tid = threadIdx.x;
    if (bx < 960) {
        // cast+transpose lin[ts][k][n] -> Lt[ts][n][k] bf16
        int ts = bx >> 6, rem = bx & 63;
        int kt = rem >> 3, nt = rem & 7;
        const float* src = lr + (size_t)ts * DMD * 512;
        unsigned short* dst = Lt + (size_t)ts * DMD * 512;
        int r = tid >> 2, c4 = tid & 3;
#pragma unroll
        for (int i = 0; i < 4; i++) {
            float4 v = *(const float4*)&src[(size_t)(kt * 64 + r) * 512 + nt * 64 + c4 * 16 + i * 4];
            *(float4*)&Tf[r][c4 * 16 + i * 4] = v;
        }
        __syncthreads();
        unsigned short tmp[16];
#pragma unroll
        for (int i = 0; i < 16; i++) tmp[i] = f2bf(Tf[c4 * 16 + i][r]);
        u16x8 o0, o1;
#pragma unroll
        for (int i = 0; i < 8; i++) { o0[i] = tmp[i]; o1[i] = tmp[8 + i]; }
        unsigned short* dp = &dst[(size_t)(nt * 64 + r) * 512 + kt * 64 + c4 * 16];
        *(u16x8*)&dp[0] = o0;
        *(u16x8*)&dp[8] = o1;
    } else if (bx < 960 + 2 * NCLS * NH) {
        int bid = bx - 960;
        int w = bid / (NCLS * NH);
        int rem = bid % (NCLS * NH);
        int c = rem / NH, h = rem % NH;
        const float* W = w ? W2 : W1;
        const float* a = w ? al2 : al1;
        unsigned short* outp = (w ? W2bt : W1bt) + (((size_t)c * NH + h) << 12);
        float vals[4], mx = -1e30f;
#pragma unroll
        for (int bb = 0; bb < 4; bb++) { vals[bb] = a[(c * 4 + bb) * NH + h]; mx = fmaxf(mx, vals[bb]); }
        float ssum = 0.f;
#pragma unroll
        for (int bb = 0; bb < 4; bb++) { vals[bb] = __expf(vals[bb] - mx); ssum += vals[bb]; }
        float inv = 1.0f / ssum;
        float s0 = vals[0] * inv, s1 = vals[1] * inv, s2 = vals[2] * inv, s3 = vals[3] * inv;
        const float* p0 = W + (size_t)(0 * NH + h) * 4096;
        const float* p1 = W + (size_t)(1 * NH + h) * 4096;
        const float* p2 = W + (size_t)(2 * NH + h) * 4096;
        const float* p3 = W + (size_t)(3 * NH + h) * 4096;
        for (int e = tid; e < 4096; e += 256) {
            float v = s0 * p0[e] + s1 * p1[e] + s2 * p2[e] + s3 * p3[e];
            int mm = e >> 6, nn = e & 63;
            outp[nn * 64 + mm] = f2bf(v);     // transposed store
        }
    } else if (bx < 960 + 2 * NCLS * NH + 96) {
        // cast q/k/v -> Xc bf16 [t][b][n][512]
        int bid = bx - (960 + 2 * NCLS * NH);   // 0..95
        int t = bid / 32, rem = bid % 32;
        int b = rem / 16, rg = rem % 16;
        int row = tid >> 2, part = tid & 3;
        const float* X = (t == 0) ? qr : ((t == 1) ? kr : vr);
        const float* src = X + ((size_t)b * NN + rg * 64 + row) * DMD + part * 128;
        unsigned short* dst = Xc + (((size_t)t * BQ + b) * NN + rg * 64 + row) * DMD + part * 128;
#pragma unroll
        for (int i = 0; i < 128; i += 8) {
            float4 v0 = *(const float4*)&src[i];
            float4 v1 = *(const float4*)&src[i + 4];
            u16x8 o;
            o[0] = f2bf(v0.x); o[1] = f2bf(v0.y); o[2] = f2bf(v0.z); o[3] = f2bf(v0.w);
            o[4] = f2bf(v1.x); o[5] = f2bf(v1.y); o[6] = f2bf(v1.z); o[7] = f2bf(v1.w);
            *(u16x8*)&dst[i] = o;
        }
    } else {
        // ---- setup (single block): dtype detect, bucketize, perm, masks
        if (tid < 5) det[tid] = 0;
        if (tid < BQ * NSEL) { cnts[tid / NSEL][tid % NSEL] = 0; offs[tid / NSEL][tid % NSEL] = 0; }
        __syncthreads();
        const int* b32 = (const int*)b_seq_r;
        const unsigned char* mb = (const unsigned char*)mask_r;
        const int* m32 = (const int*)mask_r;
        if (tid < 64) {
            if (b32[2 * tid + 1] != 0) atomicOr(&det[0], 1);
            if (b32[2 * tid] != 0)     atomicOr(&det[1], 1);
            if (m32[2 * tid + 1] != 0) atomicOr(&det[3], 1);
            if (m32[2 * tid] != 0)     atomicOr(&det[4], 1);
        }
        if ((tid & 3) != 0 && mb[tid] != 0) atomicOr(&det[2], 1);
        __syncthreads();
        int bsI64 = (det[0] == 0 && det[1] != 0);
        int mk = det[2] ? 1 : ((det[3] == 0 && det[4] != 0) ? 2 : 0);

        for (int g = tid; g < BQ * NN; g += 256) {
            int m = (mk == 1) ? (mb[g] != 0) : ((mk == 2) ? (m32[2 * g] != 0) : (m32[g] != 0));
            maskI[g] = m;
            int bs = bsI64 ? b32[2 * g] : b32[g];
            bs = bs < 0 ? 0 : (bs > 4 ? 4 : bs);
            atomicAdd(&cnts[g / NN][bs], 1);
        }
        __syncthreads();
        if (tid == 0) {
            for (int b = 0; b < BQ; b++) {
                int acc = 0;
                for (int c = 0; c < NSEL; c++) {
                    sstart[b][c] = acc;
                    acc += ((cnts[b][c] + 63) / 64) * 64;
                }
                sstart[b][NSEL] = acc;
                for (int c = 0; c <= NSEL; c++) startPad[b * (NSEL + 1) + c] = sstart[b][c];
            }
        }
        __syncthreads();
        for (int g = tid; g < BQ * NP; g += 256) {
            perm[g] = -1;
            int b = g / NP, sslot = g % NP;
            int c = 0;
            for (int cc = 1; cc < NSEL; cc++) if (sslot >= sstart[b][cc]) c = cc;
            rowc[g] = c;
        }
        __syncthreads();
        for (int g = tid; g < BQ * NN; g += 256) {
            int b = g / NN, n = g % NN;
            int bs = bsI64 ? b32[2 * g] : b32[g];
            bs = bs < 0 ? 0 : (bs > 4 ? 4 : bs);
            int pos = sstart[b][bs] + atomicAdd(&offs[b][bs], 1);
            perm[b * NP + pos] = n;
        }
        __syncthreads();
        for (int g = tid; g < BQ * NP; g += 256) {
            int tok = perm[g];
            maskP[g] = (tok < 0) ? 2 : maskI[(g / NP) * NN + tok];
        }
    }
}

// ---------------------------------------------------------------- QKV projection, MFMA bf16, XCD-aligned with k_attn
__global__ __launch_bounds__(256) void k_proj(
    const unsigned short* __restrict__ Xc,
    const unsigned short* __restrict__ Lt,
    const int* __restrict__ perm, const int* __restrict__ rowc, const int* __restrict__ startPad,
    unsigned short* __restrict__ Qb, unsigned short* __restrict__ Kb,
    unsigned short* __restrict__ Vt)
{
    int bid = blockIdx.x;
    int xcd = bid & 7, local = bid >> 3;          // 0..59
    int t = local / NPT, ti = local % NPT;
    int qtr = xcd & 3, b = xcd >> 2;

    int nTot = startPad[b * (NSEL + 1) + NSEL];
    if (ti * 64 >= nTot) return;
    int sel = rowc[b * NP + ti * 64];
    const unsigned short* XcT = Xc + ((size_t)t * BQ + b) * NN * DMD;
    const unsigned short* L = Lt + (size_t)(t * NSEL + sel) * DMD * 512;   // [n][k] bf16

    __shared__ __align__(16) unsigned short Xb[64][72];
    __shared__ __align__(16) unsigned short Lb[128][72];
    __shared__ int toks[64];

    int tid = threadIdx.x;
    int wave = tid >> 6, lane = tid & 63;
    int m = lane & 15, q = lane >> 4;
    if (tid < 64) toks[tid] = perm[b * NP + ti * 64 + tid];
    __syncthreads();

    int xr = tid >> 2, xc0 = (tid & 3) * 16;
    int xtok = toks[xr];
    const unsigned short* xbase = (xtok >= 0) ? &XcT[(size_t)xtok * DMD] : (const unsigned short*)0;
    int ln = tid >> 1, lhf = tid & 1;
    const unsigned short* lbase = &L[(size_t)(qtr * 128 + ln) * 512 + lhf * 32];

    u16x8 rx0 = {0, 0, 0, 0, 0, 0, 0, 0}, rx1 = {0, 0, 0, 0, 0, 0, 0, 0};
    u16x8 rl0, rl1, rl2, rl3;
    if (xbase) { rx0 = *(const u16x8*)&xbase[xc0]; rx1 = *(const u16x8*)&xbase[xc0 + 8]; }
    rl0 = *(const u16x8*)&lbase[0];  rl1 = *(const u16x8*)&lbase[8];
    rl2 = *(const u16x8*)&lbase[16]; rl3 = *(const u16x8*)&lbase[24];

    f32x4 acc[4][2];
#pragma unroll
    for (int mt = 0; mt < 4; mt++) { acc[mt][0] = {0, 0, 0, 0}; acc[mt][1] = {0, 0, 0, 0}; }

    for (int kb = 0; kb < DMD; kb += 64) {
        *(u16x8*)&Xb[xr][xc0] = rx0;
        *(u16x8*)&Xb[xr][xc0 + 8] = rx1;
        *(u16x8*)&Lb[ln][lhf * 32 + 0]  = rl0;
        *(u16x8*)&Lb[ln][lhf * 32 + 8]  = rl1;
        *(u16x8*)&Lb[ln][lhf * 32 + 16] = rl2;
        *(u16x8*)&Lb[ln][lhf * 32 + 24] = rl3;
        __syncthreads();
        if (kb + 64 < DMD) {   // prefetch next slab (overlaps MFMAs)
            int nk = kb + 64;
            if (xbase) { rx0 = *(const u16x8*)&xbase[nk + xc0]; rx1 = *(const u16x8*)&xbase[nk + xc0 + 8]; }
            rl0 = *(const u16x8*)&lbase[nk];      rl1 = *(const u16x8*)&lbase[nk + 8];
            rl2 = *(const u16x8*)&lbase[nk + 16]; rl3 = *(const u16x8*)&lbase[nk + 24];
        }
#pragma unroll
        for (int kc = 0; kc < 64; kc += 32) {
            bf16x8 bf0 = *(const bf16x8*)&Lb[wave * 32 + m][kc + q * 8];
            bf16x8 bf1 = *(const bf16x8*)&Lb[wave * 32 + 16 + m][kc + q * 8];
#pragma unroll
            for (int mt = 0; mt < 4; mt++) {
                bf16x8 a = *(const bf16x8*)&Xb[mt * 16 + m][kc + q * 8];
                acc[mt][0] = __builtin_amdgcn_mfma_f32_16x16x32_bf16(a, bf0, acc[mt][0], 0, 0, 0);
                acc[mt][1] = __builtin_amdgcn_mfma_f32_16x16x32_bf16(a, bf1, acc[mt][1], 0, 0, 0);
            }
        }
        __syncthreads();
    }

    if (t < 2) {
        unsigned short* O = (t == 0) ? Qb : Kb;
#pragma unroll
        for (int mt = 0; mt < 4; mt++)
#pragma unroll
            for (int nt = 0; nt < 2; nt++)
#pragma unroll
                for (int gg = 0; gg < 4; gg++) {
                    int i = mt * 16 + q * 4 + gg;
                    int hk = qtr * 128 + wave * 32 + nt * 16 + m;
                    int h = hk >> 6, k0 = hk & 63;
                    O[(((size_t)b * NH + h) * NP + ti * 64 + i) * 64 + k0] = f2bf(acc[mt][nt][gg]);
                }
    } else {
        // transpose via Lb (dead), write Vt[b][h][d][ip] coalesced
#pragma unroll
        for (int mt = 0; mt < 4; mt++)
#pragma unroll
            for (int nt = 0; nt < 2; nt++)
#pragma unroll
                for (int gg = 0; gg < 4; gg++)
                    Lb[wave * 32 + nt * 16 + m][mt * 16 + q * 4 + gg] = f2bf(acc[mt][nt][gg]);
        __syncthreads();
        int hkl = tid >> 1, hf = tid & 1;
        int hk = qtr * 128 + hkl;
        int h = hk >> 6, d = hk & 63;
        unsigned short* vp = Vt + (((size_t)b * NH + h) * DKK + d) * NP + ti * 64 + hf * 32;
#pragma unroll
        for (int s = 0; s < 4; s++)
            *(u16x8*)&vp[s * 8] = *(const u16x8*)&Lb[hkl][hf * 32 + s * 8];
    }
}

// ---------------------------------------------------------------- fused attention: 512 threads, XCD-swizzled
// Phases: 0b Q·W1 -> qloc | 1A QK^T max pass | 1B QK^T recompute + exp -> S | 3 per-class PV -> u | 4 u·W2 -> out
// TWO-PASS scores: round-2's sarr[3][4][4] (48 f32 live across the phase-1/2 barrier) starved the
// kernel to VGPR=56, serializing the 8-wide K-load batches (load->mfma->load chains at L2/L3
// latency). Recomputing QK^T in pass B (bitwise-identical MFMA) frees those registers so the
// kreg[8] batch actually materializes. MFMA cost doubles from a 4%-util base: cheap.
// qloc now aliases u (dead until phase 3), NOT S, since pass B reads qloc while writing S.
__global__ __launch_bounds__(512, 4) void k_attn(
    const unsigned short* __restrict__ Qb, const unsigned short* __restrict__ Kb,
    const unsigned short* __restrict__ Vt, const unsigned short* __restrict__ W1bt,
    const unsigned short* __restrict__ W2bt,
    const int* __restrict__ perm, const int* __restrict__ rowc, const int* __restrict__ startPad,
    const int* __restrict__ maskI, const int* __restrict__ maskP,
    float* __restrict__ out)
{
    int bid = blockIdx.x;
    int xcd = bid & 7, local = bid >> 3;          // 0..159
    int bh = xcd * 2 + (local >= 80 ? 1 : 0);
    int it = (local >= 80) ? (local - 80) : local;
    int b = bh >> 3, h = bh & 7;
    int nTot = startPad[b * (NSEL + 1) + NSEL];
    int i0 = it * 16;
    if (i0 >= nTot) return;
    int r = rowc[b * NP + i0];
    int tiles = nTot >> 6;

    // ---- LDS (53224 B): S(|pbuf) | u(|qloc) | wred | wsum | tilec | cstart | mrow | toki
    __shared__ __align__(16) char smem[16 * SSp * 2 + NSEL * 16 * QLS * 2 + 1024 + 4 * (NPT + 6 + 16 + 16)];
    unsigned short (*S)[SSp] = (unsigned short (*)[SSp])smem;                 // pass 1B write, phase 3 read
    float (*pbuf)[16][64] = (float (*)[16][64])smem;                          // phase 4 (aliases S)
    unsigned short (*u)[16][QLS] = (unsigned short (*)[16][QLS])(smem + 16 * SSp * 2);   // phases 3-4
    unsigned short (*qloc)[16][QLS] = (unsigned short (*)[16][QLS])(smem + 16 * SSp * 2); // phases 0b-1B (aliases u)
    char* tail = smem + 16 * SSp * 2 + NSEL * 16 * QLS * 2;
    float (*wred)[16] = (float (*)[16])tail;
    float (*wsum)[16] = (float (*)[16])(tail + 512);
    int* tilec = (int*)(tail + 1024);
    int* cstart = tilec + NPT;
    int* mrow = cstart + 6;
    int* toki = mrow + 16;

    int tid = threadIdx.x;
    int wave = tid >> 6, lane = tid & 63;
    int m = lane & 15, q = lane >> 4;

    const int* permB = perm + b * NP;
    const unsigned short* QbB = Qb + (size_t)bh * NP * 64;
    const unsigned short* KbB = Kb + (size_t)bh * NP * 64;
    const unsigned short* VtB = Vt + (size_t)bh * DKK * NP;      // [d][jp]
    const int* maskPB = maskP + b * NP;

    if (tid < NPT) tilec[tid] = rowc[b * NP + tid * 64];
    else if (tid >= 32 && tid < 38) cstart[tid - 32] = startPad[b * (NSEL + 1) + (tid - 32)];
    else if (tid >= 64 && tid < 80) {
        int rr = tid - 64;
        int tok = permB[i0 + rr];
        toki[rr] = tok;
        mrow[rr] = (tok >= 0) ? maskI[b * NN + tok] : 0;
    }

    // ---- phase 0b: qloc[c][i][n] = Q . W1m[cls(r,c)]; 8 waves = {c-half} x {n-subtile}
    {
        const unsigned short* qa = &QbB[(size_t)(i0 + m) * 64 + q * 8];
        bf16x8 a0 = *(const bf16x8*)qa;
        bf16x8 a1 = *(const bf16x8*)(qa + 32);
        int sub = wave & 3;
        int c0 = (wave >> 2) ? 3 : 0;
        int c1 = (wave >> 2) ? 5 : 3;
        for (int c = c0; c < c1; c++) {
            int cls = clsOf(r, c);
            const unsigned short* wb = W1bt + (((size_t)cls * NH + h) << 12)
                                     + (size_t)(sub * 16 + m) * 64 + q * 8;
            bf16x8 b0 = *(const bf16x8*)wb;
            bf16x8 b1 = *(const bf16x8*)(wb + 32);
            f32x4 acc = {0.f, 0.f, 0.f, 0.f};
            acc = __builtin_amdgcn_mfma_f32_16x16x32_bf16(a0, b0, acc, 0, 0, 0);
            acc = __builtin_amdgcn_mfma_f32_16x16x32_bf16(a1, b1, acc, 0, 0, 0);
#pragma unroll
            for (int g = 0; g < 4; g++)
                qloc[c][q * 4 + g][sub * 16 + m] = f2bf(acc[g]);
        }
    }
    __syncthreads();

    int mrow4[4];
#pragma unroll
    for (int g = 0; g < 4; g++) mrow4[g] = mrow[q * 4 + g];

    // ---- pass 1A: QK^T, row max only (no stored scores -> no register starvation)
    float lmax[4] = {-INFINITY, -INFINITY, -INFINITY, -INFINITY};
#pragma unroll
    for (int tt = 0; tt < MAXT; tt++) {
        int jt = wave + tt * 8;
        if (jt < tiles) {                          // wave-uniform branch
            int c = tilec[jt];
            int jb = jt * 64;
            const unsigned short* qa = &qloc[c][m][q * 8];
            bf16x8 a0 = *(const bf16x8*)qa;
            bf16x8 a1 = *(const bf16x8*)(qa + 32);
            bf16x8 kreg[8];
            int mj4[4];
#pragma unroll
            for (int nb = 0; nb < 4; nb++) {
                int j = jb + nb * 16 + m;
                const unsigned short* kb = &KbB[(size_t)j * 64 + q * 8];
                kreg[nb * 2]     = *(const bf16x8*)kb;
                kreg[nb * 2 + 1] = *(const bf16x8*)(kb + 32);
                mj4[nb] = maskPB[j];
            }
#pragma unroll
            for (int nb = 0; nb < 4; nb++) {
                f32x4 acc = {0.f, 0.f, 0.f, 0.f};
                acc = __builtin_amdgcn_mfma_f32_16x16x32_bf16(a0, kreg[nb * 2], acc, 0, 0, 0);
                acc = __builtin_amdgcn_mfma_f32_16x16x32_bf16(a1, kreg[nb * 2 + 1], acc, 0, 0, 0);
                int mj = mj4[nb];
#pragma unroll
                for (int g = 0; g < 4; g++) {
                    float sv;
                    if (mj == 2)             sv = -INFINITY;      // padding slot
                    else if (mrow4[g] && mj) sv = acc[g] * 0.125f;
                    else                     sv = -1e30f;         // reference's masked value
                    lmax[g] = fmaxf(lmax[g], sv);
                }
            }
        }
    }
#pragma unroll
    for (int g = 0; g < 4; g++) {
        float v = lmax[g];
#pragma unroll
        for (int o = 1; o < 16; o <<= 1) v = fmaxf(v, __shfl_xor(v, o));
        lmax[g] = v;
    }
    if (m == 0) {
#pragma unroll
        for (int g = 0; g < 4; g++) wred[wave][q * 4 + g] = lmax[g];
    }
    __syncthreads();

    // ---- pass 1B: recompute QK^T (bitwise identical), exp with global max, write S, row sums
    float mx4[4], lsum[4] = {0.f, 0.f, 0.f, 0.f};
#pragma unroll
    for (int g = 0; g < 4; g++) {
        int i = q * 4 + g;
        float v = wred[0][i];
#pragma unroll
        for (int w2 = 1; w2 < 8; w2++) v = fmaxf(v, wred[w2][i]);
        mx4[g] = v;
    }
#pragma unroll
    for (int tt = 0; tt < MAXT; tt++) {
        int jt = wave + tt * 8;
        if (jt < tiles) {                          // wave-uniform branch
            int c = tilec[jt];
            int jb = jt * 64;
            const unsigned short* qa = &qloc[c][m][q * 8];
            bf16x8 a0 = *(const bf16x8*)qa;
            bf16x8 a1 = *(const bf16x8*)(qa + 32);
            bf16x8 kreg[8];
            int mj4[4];
#pragma unroll
            for (int nb = 0; nb < 4; nb++) {
                int j = jb + nb * 16 + m;
                const unsigned short* kb = &KbB[(size_t)j * 64 + q * 8];
                kreg[nb * 2]     = *(const bf16x8*)kb;
                kreg[nb * 2 + 1] = *(const bf16x8*)(kb + 32);
                mj4[nb] = maskPB[j];
            }
#pragma unroll
            for (int nb = 0; nb < 4; nb++) {
                f32x4 acc = {0.f, 0.f, 0.f, 0.f};
                acc = __builtin_amdgcn_mfma_f32_16x16x32_bf16(a0, kreg[nb * 2], acc, 0, 0, 0);
                acc = __builtin_amdgcn_mfma_f32_16x16x32_bf16(a1, kreg[nb * 2 + 1], acc, 0, 0, 0);
                int mj = mj4[nb];
                int j = jb + nb * 16 + m;
#pragma unroll
                for (int g = 0; g < 4; g++) {
                    float sv;
                    if (mj == 2)             sv = -INFINITY;
                    else if (mrow4[g] && mj) sv = acc[g] * 0.125f;
                    else                     sv = -1e30f;
                    float p = __expf(sv - mx4[g]);   // -inf -> 0
                    lsum[g] += p;
                    S[q * 4 + g][j] = f2bf(p);
                }
            }
        }
    }
#pragma unroll
    for (int g = 0; g < 4; g++) {
        float v = lsum[g];
#pragma unroll
        for (int o = 1; o < 16; o <<= 1) v += __shfl_xor(v, o);
        lsum[g] = v;
    }
    if (m == 0) {
#pragma unroll
        for (int g = 0; g < 4; g++) wsum[wave][q * 4 + g] = lsum[g];
    }
    __syncthreads();   // qloc dead from here; S fully written

    // ---- phase 3: per-class PV into u; wave = (kw, c-half)
    //      dynamic split point sc balances tile counts between wave halves;
    //      1-deep register prefetch of S-row + V-row carried across class boundaries.
    {
        int kw = wave & 3, chalf = wave >> 2;
        int db = kw * 16;
        int nT2 = cstart[5];
        int sc = 1, best = 0x7fffffff;
#pragma unroll
        for (int c = 1; c <= 4; c++) {
            int d = 2 * cstart[c] - nT2;
            d = d < 0 ? -d : d;
            if (d < best) { best = d; sc = c; }
        }
        int cb = chalf ? sc : 0, ce = chalf ? 5 : sc;
        int t0 = cstart[cb] >> 6, tEnd = cstart[ce] >> 6;
        const unsigned short* Srow = &S[m][q * 8];
        const unsigned short* Vrow = &VtB[(size_t)(db + m) * NP + q * 8];
        bf16x8 a0 = {}, a1 = {}, b0 = {}, b1 = {};
        if (t0 < tEnd) {
            int jb = t0 * 64;
            a0 = *(const bf16x8*)&Srow[jb];  a1 = *(const bf16x8*)&Srow[jb + 32];
            b0 = *(const bf16x8*)&Vrow[jb];  b1 = *(const bf16x8*)&Vrow[jb + 32];
        }
        int tcur = t0;
        for (int c = cb; c < ce; c++) {
            int ct1 = cstart[c + 1] >> 6;
            f32x4 ae = {0.f, 0.f, 0.f, 0.f};
            f32x4 ao = {0.f, 0.f, 0.f, 0.f};
            while (tcur < ct1) {
                bf16x8 ca0 = a0, ca1 = a1, cb0 = b0, cb1 = b1;
                int tn = tcur + 1;
                if (tn < tEnd) {             // prefetch next tile (crosses class boundary)
                    int jb = tn * 64;
                    a0 = *(const bf16x8*)&Srow[jb];  a1 = *(const bf16x8*)&Srow[jb + 32];
                    b0 = *(const bf16x8*)&Vrow[jb];  b1 = *(const bf16x8*)&Vrow[jb + 32];
                }
                ae = __builtin_amdgcn_mfma_f32_16x16x32_bf16(ca0, cb0, ae, 0, 0, 0);
                ao = __builtin_amdgcn_mfma_f32_16x16x32_bf16(ca1, cb1, ao, 0, 0, 0);
                tcur++;
            }
#pragma unroll
            for (int g = 0; g < 4; g++)
                u[c][q * 4 + g][db + m] = f2bf(ae[g] + ao[g]);
        }
    }
    __syncthreads();   // S dead from here; pbuf region reusable

    // ---- phase 4: out = (sum_c u[c] . W2m[cls(r,c)]) ; wave = (kw, c-half); pbuf combine
    {
        int kw = wave & 3, p = wave >> 2;
        int cb = p ? 3 : 0, ce = p ? 5 : 3;
        f32x4 acc = {0.f, 0.f, 0.f, 0.f};
        for (int c = cb; c < ce; c++) {
            int cls = clsOf(r, c);
            const unsigned short* ua = &u[c][m][q * 8];
            bf16x8 a0 = *(const bf16x8*)ua;
            bf16x8 a1 = *(const bf16x8*)(ua + 32);
            const unsigned short* wb = W2bt + (((size_t)cls * NH + h) << 12)
                                     + (size_t)(kw * 16 + m) * 64 + q * 8;
            bf16x8 b0 = *(const bf16x8*)wb;
            bf16x8 b1 = *(const bf16x8*)(wb + 32);
            acc = __builtin_amdgcn_mfma_f32_16x16x32_bf16(a0, b0, acc, 0, 0, 0);
            acc = __builtin_amdgcn_mfma_f32_16x16x32_bf16(a1, b1, acc, 0, 0, 0);
        }
#pragma unroll
        for (int g = 0; g < 4; g++)
            pbuf[p][q * 4 + g][kw * 16 + m] = acc[g];
    }
    __syncthreads();

    // ---- epilogue: combine halves, normalize, nontemporal store (keep K/V resident in L2)
    for (int idx = tid; idx < 16 * 64; idx += 512) {
        int i = idx >> 6, k = idx & 63;
        int tok = toki[i];
        if (tok >= 0) {
            float s = wsum[0][i] + wsum[1][i] + wsum[2][i] + wsum[3][i]
                    + wsum[4][i] + wsum[5][i] + wsum[6][i] + wsum[7][i];
            float v = pbuf[0][i][k] + pbuf[1][i][k];
            __builtin_nontemporal_store(v / s, &out[((size_t)b * NN + tok) * (NH * DKK) + h * DKK + k]);
        }
    }
}

// ---------------------------------------------------------------- launch
extern "C" void kernel_launch(void* const* d_in, const int* in_sizes, int n_in,
                              void* d_out, int out_size, void* d_ws, size_t ws_size,
                              hipStream_t stream)
{
    const float* qr  = (const float*)d_in[0];
    const float* kr  = (const float*)d_in[1];
    const float* vr  = (const float*)d_in[2];
    const void* bsr  = d_in[3];
    const void* mkr  = d_in[4];
    const float* lr  = (const float*)d_in[5];
    const float* w1r = (const float*)d_in[6];
    const float* a1r = (const float*)d_in[7];
    const float* w2r = (const float*)d_in[8];
    const float* a2r = (const float*)d_in[9];
    float* out = (float*)d_out;

    char* w = (char*)d_ws;
    int* maskI    = (int*)w;
    int* perm     = maskI + BQ * NN;
    int* rowc     = perm + BQ * NP;
    int* startPad = rowc + BQ * NP;
    int* maskP    = startPad + 12;
    unsigned short* W1bt = (unsigned short*)(w + 65536);
    unsigned short* W2bt = W1bt + (size_t)NCLS * NH * 4096;
    unsigned short* Qb   = (unsigned short*)(w + 2359296);
    unsigned short* Kb   = Qb + (size_t)BQ * NH * NP * 64;
    unsigned short* Vt   = Kb + (size_t)BQ * NH * NP * 64;           // [b][h][d][ip]
    unsigned short* Lt   = (unsigned short*)(w + 10616832);
    unsigned short* Xc   = (unsigned short*)(w + 26345472);          // total ~32.6 MB

    hipLaunchKernelGGL(k_prep, dim3(960 + 2 * NCLS * NH + 96 + 1), dim3(256), 0, stream,
                       lr, Lt, w1r, w2r, a1r, a2r, W1bt, W2bt, qr, kr, vr, Xc,
                       bsr, mkr, maskI, perm, rowc, startPad, maskP);
    hipLaunchKernelGGL(k_proj, dim3(8 * 3 * NPT), dim3(256), 0, stream,
                       Xc, Lt, perm, rowc, startPad, Qb, Kb, Vt);
    hipLaunchKernelGGL(k_attn, dim3(8 * 2 * 80), dim3(512), 0, stream,
                       Qb, Kb, Vt, W1bt, W2bt, perm, rowc, startPad, maskI, maskP, out);
}

// Round 5
// 186.081 us; speedup vs baseline: 1.1285x; 1.0558x over previous
//
#include <hip/hip_runtime.h>
#include <hip/hip_bf16.h>
#include <math.h>

#define BQ   2      // batch
#define NN   1024   // seq len
#define DMD  512    // d_model
#define NH   8      // heads
#define DKK  64     // head dim
#define NSEL 5      // NB+1 block values (0..4)
#define NCLS 17     // block-pair classes
#define NP   1280   // padded per-batch capacity: nTot = sum(ceil(c_i/64)*64) <= 1339 and %64==0 -> <=1280
#define NPT  20     // NP/64 tiles
#define MAXT 3      // max key-tiles per wave in k_attn (ceil(20/8))
#define SSp  1284   // S row stride (shorts): 2568B = 642 words == 2 mod 32 banks, conflict-free shift
#define QLS  68     // qloc/u row stride (shorts)

typedef __attribute__((ext_vector_type(8))) short bf16x8;
typedef __attribute__((ext_vector_type(8))) unsigned short u16x8;
typedef __attribute__((ext_vector_type(4))) float f32x4;

__device__ __forceinline__ int clsOf(int r, int c) { return (r == 0 || c == 0) ? 0 : ((r - 1) * 4 + c); }

__device__ __forceinline__ unsigned short f2bf(float x) {
    __hip_bfloat16 h = __float2bfloat16(x);
    return *reinterpret_cast<unsigned short*>(&h);
}

// ---------------------------------------------------------------- prep: lin cast (960) + qkv cast (96) + setup (1)
// wmix moved to k_proj's grid: it has no k_prep deps and its consumer (k_attn) runs after k_proj.
__global__ __launch_bounds__(256) void k_prep(
    const float* __restrict__ lr, unsigned short* __restrict__ Lt,
    const float* __restrict__ qr, const float* __restrict__ kr, const float* __restrict__ vr,
    unsigned short* __restrict__ Xc,
    const void* __restrict__ b_seq_r, const void* __restrict__ mask_r,
    int* __restrict__ maskI, int* __restrict__ perm, int* __restrict__ rowc,
    int* __restrict__ startPad, int* __restrict__ maskP)
{
    __shared__ float Tf[64][68];
    __shared__ int det[5];
    __shared__ int cnts[BQ][NSEL];
    __shared__ int offs[BQ][NSEL];
    __shared__ int sstart[BQ][NSEL + 1];
    int bx = blockIdx.x;
    int tid = threadIdx.x;
    if (bx < 960) {
        // cast+transpose lin[ts][k][n] -> Lt[ts][n][k] bf16
        int ts = bx >> 6, rem = bx & 63;
        int kt = rem >> 3, nt = rem & 7;
        const float* src = lr + (size_t)ts * DMD * 512;
        unsigned short* dst = Lt + (size_t)ts * DMD * 512;
        int r = tid >> 2, c4 = tid & 3;
#pragma unroll
        for (int i = 0; i < 4; i++) {
            float4 v = *(const float4*)&src[(size_t)(kt * 64 + r) * 512 + nt * 64 + c4 * 16 + i * 4];
            *(float4*)&Tf[r][c4 * 16 + i * 4] = v;
        }
        __syncthreads();
        unsigned short tmp[16];
#pragma unroll
        for (int i = 0; i < 16; i++) tmp[i] = f2bf(Tf[c4 * 16 + i][r]);
        u16x8 o0, o1;
#pragma unroll
        for (int i = 0; i < 8; i++) { o0[i] = tmp[i]; o1[i] = tmp[8 + i]; }
        unsigned short* dp = &dst[(size_t)(nt * 64 + r) * 512 + kt * 64 + c4 * 16];
        *(u16x8*)&dp[0] = o0;
        *(u16x8*)&dp[8] = o1;
    } else if (bx < 960 + 96) {
        // cast q/k/v -> Xc bf16 [t][b][n][512]
        int bid = bx - 960;                     // 0..95
        int t = bid / 32, rem = bid % 32;
        int b = rem / 16, rg = rem % 16;
        int row = tid >> 2, part = tid & 3;
        const float* X = (t == 0) ? qr : ((t == 1) ? kr : vr);
        const float* src = X + ((size_t)b * NN + rg * 64 + row) * DMD + part * 128;
        unsigned short* dst = Xc + (((size_t)t * BQ + b) * NN + rg * 64 + row) * DMD + part * 128;
#pragma unroll
        for (int i = 0; i < 128; i += 8) {
            float4 v0 = *(const float4*)&src[i];
            float4 v1 = *(const float4*)&src[i + 4];
            u16x8 o;
            o[0] = f2bf(v0.x); o[1] = f2bf(v0.y); o[2] = f2bf(v0.z); o[3] = f2bf(v0.w);
            o[4] = f2bf(v1.x); o[5] = f2bf(v1.y); o[6] = f2bf(v1.z); o[7] = f2bf(v1.w);
            *(u16x8*)&dst[i] = o;
        }
    } else {
        // ---- setup (single block): dtype detect, bucketize, perm, masks
        if (tid < 5) det[tid] = 0;
        if (tid < BQ * NSEL) { cnts[tid / NSEL][tid % NSEL] = 0; offs[tid / NSEL][tid % NSEL] = 0; }
        __syncthreads();
        const int* b32 = (const int*)b_seq_r;
        const unsigned char* mb = (const unsigned char*)mask_r;
        const int* m32 = (const int*)mask_r;
        if (tid < 64) {
            if (b32[2 * tid + 1] != 0) atomicOr(&det[0], 1);
            if (b32[2 * tid] != 0)     atomicOr(&det[1], 1);
            if (m32[2 * tid + 1] != 0) atomicOr(&det[3], 1);
            if (m32[2 * tid] != 0)     atomicOr(&det[4], 1);
        }
        if ((tid & 3) != 0 && mb[tid] != 0) atomicOr(&det[2], 1);
        __syncthreads();
        int bsI64 = (det[0] == 0 && det[1] != 0);
        int mk = det[2] ? 1 : ((det[3] == 0 && det[4] != 0) ? 2 : 0);

        for (int g = tid; g < BQ * NN; g += 256) {
            int m = (mk == 1) ? (mb[g] != 0) : ((mk == 2) ? (m32[2 * g] != 0) : (m32[g] != 0));
            maskI[g] = m;
            int bs = bsI64 ? b32[2 * g] : b32[g];
            bs = bs < 0 ? 0 : (bs > 4 ? 4 : bs);
            atomicAdd(&cnts[g / NN][bs], 1);
        }
        __syncthreads();
        if (tid == 0) {
            for (int b = 0; b < BQ; b++) {
                int acc = 0;
                for (int c = 0; c < NSEL; c++) {
                    sstart[b][c] = acc;
                    acc += ((cnts[b][c] + 63) / 64) * 64;
                }
                sstart[b][NSEL] = acc;
                for (int c = 0; c <= NSEL; c++) startPad[b * (NSEL + 1) + c] = sstart[b][c];
            }
        }
        __syncthreads();
        for (int g = tid; g < BQ * NP; g += 256) {
            perm[g] = -1;
            int b = g / NP, sslot = g % NP;
            int c = 0;
            for (int cc = 1; cc < NSEL; cc++) if (sslot >= sstart[b][cc]) c = cc;
            rowc[g] = c;
        }
        __syncthreads();
        for (int g = tid; g < BQ * NN; g += 256) {
            int b = g / NN, n = g % NN;
            int bs = bsI64 ? b32[2 * g] : b32[g];
            bs = bs < 0 ? 0 : (bs > 4 ? 4 : bs);
            int pos = sstart[b][bs] + atomicAdd(&offs[b][bs], 1);
            perm[b * NP + pos] = n;
        }
        __syncthreads();
        for (int g = tid; g < BQ * NP; g += 256) {
            int tok = perm[g];
            maskP[g] = (tok < 0) ? 2 : maskI[(g / NP) * NN + tok];
        }
    }
}

// ---------------------------------------------------------------- QKV projection (960 blocks) + wmix (272 blocks)
// Round-4 k_proj was 1.9 blocks/CU (~7.5 waves/CU), latency-bound on its 2-barrier-per-slab loop.
// Split: each block now 64 tok x 64 out (was 64x128): grid 480->960, LDS 56KB->18.7KB -> ~2x
// resident waves. XCD mapping preserved (xcd = bid&7 picks b,qtr that local k_attn blocks read).
__global__ __launch_bounds__(256) void k_proj(
    const unsigned short* __restrict__ Xc,
    const unsigned short* __restrict__ Lt,
    const int* __restrict__ perm, const int* __restrict__ rowc, const int* __restrict__ startPad,
    unsigned short* __restrict__ Qb, unsigned short* __restrict__ Kb,
    unsigned short* __restrict__ Vt,
    const float* __restrict__ W1, const float* __restrict__ W2,
    const float* __restrict__ al1, const float* __restrict__ al2,
    unsigned short* __restrict__ W1bt, unsigned short* __restrict__ W2bt)
{
    __shared__ __align__(16) unsigned short Xb[64][72];
    __shared__ __align__(16) unsigned short Lb[64][72];
    __shared__ int toks[64];

    int bid = blockIdx.x;
    int tid = threadIdx.x;
    if (bid >= 960) {
        // ---- wmix: W1m/W2m mixtures, transposed bf16 (moved from k_prep; no k_prep deps)
        int bid2 = bid - 960;
        int w = bid2 / (NCLS * NH);
        int rem = bid2 % (NCLS * NH);
        int c = rem / NH, h = rem % NH;
        const float* W = w ? W2 : W1;
        const float* a = w ? al2 : al1;
        unsigned short* outp = (w ? W2bt : W1bt) + (((size_t)c * NH + h) << 12);
        float vals[4], mx = -1e30f;
#pragma unroll
        for (int bb = 0; bb < 4; bb++) { vals[bb] = a[(c * 4 + bb) * NH + h]; mx = fmaxf(mx, vals[bb]); }
        float ssum = 0.f;
#pragma unroll
        for (int bb = 0; bb < 4; bb++) { vals[bb] = __expf(vals[bb] - mx); ssum += vals[bb]; }
        float inv = 1.0f / ssum;
        float s0 = vals[0] * inv, s1 = vals[1] * inv, s2 = vals[2] * inv, s3 = vals[3] * inv;
        const float* p0 = W + (size_t)(0 * NH + h) * 4096;
        const float* p1 = W + (size_t)(1 * NH + h) * 4096;
        const float* p2 = W + (size_t)(2 * NH + h) * 4096;
        const float* p3 = W + (size_t)(3 * NH + h) * 4096;
        for (int e = tid; e < 4096; e += 256) {
            float v = s0 * p0[e] + s1 * p1[e] + s2 * p2[e] + s3 * p3[e];
            int mm = e >> 6, nn = e & 63;
            outp[nn * 64 + mm] = f2bf(v);     // transposed store
        }
        return;
    }

    int xcd = bid & 7, local = bid >> 3;          // 0..119
    int t = local / 40, rem = local % 40;
    int ti = rem >> 1, half = rem & 1;
    int qtr = xcd & 3, b = xcd >> 2;

    int nTot = startPad[b * (NSEL + 1) + NSEL];
    if (ti * 64 >= nTot) return;
    int sel = rowc[b * NP + ti * 64];
    const unsigned short* XcT = Xc + ((size_t)t * BQ + b) * NN * DMD;
    const unsigned short* L = Lt + (size_t)(t * NSEL + sel) * DMD * 512;   // [n][k] bf16

    int wave = tid >> 6, lane = tid & 63;
    int m = lane & 15, q = lane >> 4;
    if (tid < 64) toks[tid] = perm[b * NP + ti * 64 + tid];
    __syncthreads();

    int xr = tid >> 2, xc0 = (tid & 3) * 16;
    int xtok = toks[xr];
    const unsigned short* xbase = (xtok >= 0) ? &XcT[(size_t)xtok * DMD] : (const unsigned short*)0;
    int lrow = tid >> 2, lc0 = (tid & 3) * 16;
    const unsigned short* lbase = &L[(size_t)(qtr * 128 + half * 64 + lrow) * 512 + lc0];

    u16x8 rx0 = {0, 0, 0, 0, 0, 0, 0, 0}, rx1 = {0, 0, 0, 0, 0, 0, 0, 0};
    u16x8 rl0, rl1;
    if (xbase) { rx0 = *(const u16x8*)&xbase[xc0]; rx1 = *(const u16x8*)&xbase[xc0 + 8]; }
    rl0 = *(const u16x8*)&lbase[0];
    rl1 = *(const u16x8*)&lbase[8];

    f32x4 acc[4];
#pragma unroll
    for (int mt = 0; mt < 4; mt++) acc[mt] = {0, 0, 0, 0};

    for (int kb = 0; kb < DMD; kb += 64) {
        *(u16x8*)&Xb[xr][xc0] = rx0;
        *(u16x8*)&Xb[xr][xc0 + 8] = rx1;
        *(u16x8*)&Lb[lrow][lc0] = rl0;
        *(u16x8*)&Lb[lrow][lc0 + 8] = rl1;
        __syncthreads();
        if (kb + 64 < DMD) {   // prefetch next slab (overlaps MFMAs)
            int nk = kb + 64;
            if (xbase) { rx0 = *(const u16x8*)&xbase[nk + xc0]; rx1 = *(const u16x8*)&xbase[nk + xc0 + 8]; }
            rl0 = *(const u16x8*)&lbase[nk];
            rl1 = *(const u16x8*)&lbase[nk + 8];
        }
#pragma unroll
        for (int kc = 0; kc < 64; kc += 32) {
            bf16x8 bfrag = *(const bf16x8*)&Lb[wave * 16 + m][kc + q * 8];
#pragma unroll
            for (int mt = 0; mt < 4; mt++) {
                bf16x8 a = *(const bf16x8*)&Xb[mt * 16 + m][kc + q * 8];
                acc[mt] = __builtin_amdgcn_mfma_f32_16x16x32_bf16(a, bfrag, acc[mt], 0, 0, 0);
            }
        }
        __syncthreads();
    }

    if (t < 2) {
        unsigned short* O = (t == 0) ? Qb : Kb;
        int hk = qtr * 128 + half * 64 + wave * 16 + m;
        int h = hk >> 6, k0 = hk & 63;
#pragma unroll
        for (int mt = 0; mt < 4; mt++)
#pragma unroll
            for (int gg = 0; gg < 4; gg++) {
                int i = mt * 16 + q * 4 + gg;
                O[(((size_t)b * NH + h) * NP + ti * 64 + i) * 64 + k0] = f2bf(acc[mt][gg]);
            }
    } else {
        // transpose via Lb (dead), write Vt[b][h][d][ip] coalesced
#pragma unroll
        for (int mt = 0; mt < 4; mt++)
#pragma unroll
            for (int gg = 0; gg < 4; gg++)
                Lb[wave * 16 + m][mt * 16 + q * 4 + gg] = f2bf(acc[mt][gg]);
        __syncthreads();
        int hkl = tid >> 2, part = tid & 3;
        int hk = qtr * 128 + half * 64 + hkl;
        int h = hk >> 6, d = hk & 63;
        unsigned short* vp = Vt + (((size_t)b * NH + h) * DKK + d) * NP + ti * 64 + part * 16;
        *(u16x8*)&vp[0] = *(const u16x8*)&Lb[hkl][part * 16];
        *(u16x8*)&vp[8] = *(const u16x8*)&Lb[hkl][part * 16 + 8];
    }
}

// ---------------------------------------------------------------- fused attention: 512 threads, XCD-swizzled
// Reverted verbatim to the round-2 kernel (78.6 us measured): single-pass scores with sarr,
// (512,4) launch bounds, LDS 53224 B. Round-1 (512,6) spilled; round-3 split and round-4
// two-pass both regressed — this is the best measured fused structure.
__global__ __launch_bounds__(512, 4) void k_attn(
    const unsigned short* __restrict__ Qb, const unsigned short* __restrict__ Kb,
    const unsigned short* __restrict__ Vt, const unsigned short* __restrict__ W1bt,
    const unsigned short* __restrict__ W2bt,
    const int* __restrict__ perm, const int* __restrict__ rowc, const int* __restrict__ startPad,
    const int* __restrict__ maskI, const int* __restrict__ maskP,
    float* __restrict__ out)
{
    int bid = blockIdx.x;
    int xcd = bid & 7, local = bid >> 3;          // 0..159
    int bh = xcd * 2 + (local >= 80 ? 1 : 0);
    int it = (local >= 80) ? (local - 80) : local;
    int b = bh >> 3, h = bh & 7;
    int nTot = startPad[b * (NSEL + 1) + NSEL];
    int i0 = it * 16;
    if (i0 >= nTot) return;
    int r = rowc[b * NP + i0];
    int tiles = nTot >> 6;

    // ---- LDS union (53224 B): S | u | wred | wsum | tilec | cstart | mrow | toki
    __shared__ __align__(16) char smem[16 * SSp * 2 + NSEL * 16 * QLS * 2 + 1024 + 4 * (NPT + 6 + 16 + 16)];
    unsigned short (*S)[SSp] = (unsigned short (*)[SSp])smem;                 // phases 2-3
    unsigned short (*qloc)[16][QLS] = (unsigned short (*)[16][QLS])smem;      // phases 0b-1 (aliases S)
    float (*pbuf)[16][64] = (float (*)[16][64])smem;                          // phase 4 (aliases S)
    unsigned short (*u)[16][QLS] = (unsigned short (*)[16][QLS])(smem + 16 * SSp * 2);
    char* tail = smem + 16 * SSp * 2 + NSEL * 16 * QLS * 2;
    float (*wred)[16] = (float (*)[16])tail;
    float (*wsum)[16] = (float (*)[16])(tail + 512);
    int* tilec = (int*)(tail + 1024);
    int* cstart = tilec + NPT;
    int* mrow = cstart + 6;
    int* toki = mrow + 16;

    int tid = threadIdx.x;
    int wave = tid >> 6, lane = tid & 63;
    int m = lane & 15, q = lane >> 4;

    const int* permB = perm + b * NP;
    const unsigned short* QbB = Qb + (size_t)bh * NP * 64;
    const unsigned short* KbB = Kb + (size_t)bh * NP * 64;
    const unsigned short* VtB = Vt + (size_t)bh * DKK * NP;      // [d][jp]
    const int* maskPB = maskP + b * NP;

    if (tid < NPT) tilec[tid] = rowc[b * NP + tid * 64];
    else if (tid >= 32 && tid < 38) cstart[tid - 32] = startPad[b * (NSEL + 1) + (tid - 32)];
    else if (tid >= 64 && tid < 80) {
        int rr = tid - 64;
        int tok = permB[i0 + rr];
        toki[rr] = tok;
        mrow[rr] = (tok >= 0) ? maskI[b * NN + tok] : 0;
    }

    // ---- phase 0b: qloc[c][i][n] = Q . W1m[cls(r,c)]; 8 waves = {c-half} x {n-subtile}
    {
        const unsigned short* qa = &QbB[(size_t)(i0 + m) * 64 + q * 8];
        bf16x8 a0 = *(const bf16x8*)qa;
        bf16x8 a1 = *(const bf16x8*)(qa + 32);
        int sub = wave & 3;
        int c0 = (wave >> 2) ? 3 : 0;
        int c1 = (wave >> 2) ? 5 : 3;
        for (int c = c0; c < c1; c++) {
            int cls = clsOf(r, c);
            const unsigned short* wb = W1bt + (((size_t)cls * NH + h) << 12)
                                     + (size_t)(sub * 16 + m) * 64 + q * 8;
            bf16x8 b0 = *(const bf16x8*)wb;
            bf16x8 b1 = *(const bf16x8*)(wb + 32);
            f32x4 acc = {0.f, 0.f, 0.f, 0.f};
            acc = __builtin_amdgcn_mfma_f32_16x16x32_bf16(a0, b0, acc, 0, 0, 0);
            acc = __builtin_amdgcn_mfma_f32_16x16x32_bf16(a1, b1, acc, 0, 0, 0);
#pragma unroll
            for (int g = 0; g < 4; g++)
                qloc[c][q * 4 + g][sub * 16 + m] = f2bf(acc[g]);
        }
    }
    __syncthreads();

    // ---- phase 1: scores in registers; batch all 8 K loads per tile before the MFMA burst
    float sarr[MAXT][4][4];
    float lmax[4] = {-INFINITY, -INFINITY, -INFINITY, -INFINITY};
    int mrow4[4];
#pragma unroll
    for (int g = 0; g < 4; g++) mrow4[g] = mrow[q * 4 + g];

#pragma unroll
    for (int tt = 0; tt < MAXT; tt++) {
        int jt = wave + tt * 8;
        bool valid = (jt < tiles);
        int jts = valid ? jt : 0;
        int c = tilec[jts];
        int jb = jts * 64;
        const unsigned short* qa = &qloc[c][m][q * 8];
        bf16x8 a0 = *(const bf16x8*)qa;
        bf16x8 a1 = *(const bf16x8*)(qa + 32);
        bf16x8 kreg[8];
        int mj4[4];
#pragma unroll
        for (int nb = 0; nb < 4; nb++) {
            int j = jb + nb * 16 + m;
            const unsigned short* kb = &KbB[(size_t)j * 64 + q * 8];
            kreg[nb * 2]     = *(const bf16x8*)kb;
            kreg[nb * 2 + 1] = *(const bf16x8*)(kb + 32);
            mj4[nb] = maskPB[j];
        }
#pragma unroll
        for (int nb = 0; nb < 4; nb++) {
            f32x4 acc = {0.f, 0.f, 0.f, 0.f};
            acc = __builtin_amdgcn_mfma_f32_16x16x32_bf16(a0, kreg[nb * 2], acc, 0, 0, 0);
            acc = __builtin_amdgcn_mfma_f32_16x16x32_bf16(a1, kreg[nb * 2 + 1], acc, 0, 0, 0);
            int mj = mj4[nb];
#pragma unroll
            for (int g = 0; g < 4; g++) {
                float sv;
                if (!valid || mj == 2)   sv = -INFINITY;      // padding / no tile
                else if (mrow4[g] && mj) sv = acc[g] * 0.125f;
                else                     sv = -1e30f;         // reference's masked value
                sarr[tt][nb][g] = sv;
                lmax[g] = fmaxf(lmax[g], sv);
            }
        }
    }
#pragma unroll
    for (int g = 0; g < 4; g++) {
        float v = lmax[g];
#pragma unroll
        for (int o = 1; o < 16; o <<= 1) v = fmaxf(v, __shfl_xor(v, o));
        lmax[g] = v;
    }
    if (m == 0) {
#pragma unroll
        for (int g = 0; g < 4; g++) wred[wave][q * 4 + g] = lmax[g];
    }
    __syncthreads();   // qloc dead from here

    // ---- phase 2: exp in regs, single P write into S, row sums (normalization deferred)
    float mx4[4], lsum[4] = {0.f, 0.f, 0.f, 0.f};
#pragma unroll
    for (int g = 0; g < 4; g++) {
        int i = q * 4 + g;
        float v = wred[0][i];
#pragma unroll
        for (int w2 = 1; w2 < 8; w2++) v = fmaxf(v, wred[w2][i]);
        mx4[g] = v;
    }
#pragma unroll
    for (int tt = 0; tt < MAXT; tt++) {
        int jt = wave + tt * 8;
        bool valid = (jt < tiles);
        int jb = jt * 64;
#pragma unroll
        for (int nb = 0; nb < 4; nb++) {
            int j = jb + nb * 16 + m;
#pragma unroll
            for (int g = 0; g < 4; g++) {
                float p = __expf(sarr[tt][nb][g] - mx4[g]);   // -inf -> 0
                lsum[g] += p;
                if (valid) S[q * 4 + g][j] = f2bf(p);
            }
        }
    }
#pragma unroll
    for (int g = 0; g < 4; g++) {
        float v = lsum[g];
#pragma unroll
        for (int o = 1; o < 16; o <<= 1) v += __shfl_xor(v, o);
        lsum[g] = v;
    }
    if (m == 0) {
#pragma unroll
        for (int g = 0; g < 4; g++) wsum[wave][q * 4 + g] = lsum[g];
    }
    __syncthreads();

    // ---- phase 3: per-class PV into u; wave = (kw, c-half)
    //      dynamic split point sc balances tile counts between wave halves;
    //      1-deep register prefetch of S-row + V-row carried across class boundaries.
    {
        int kw = wave & 3, chalf = wave >> 2;
        int db = kw * 16;
        int nT2 = cstart[5];
        int sc = 1, best = 0x7fffffff;
#pragma unroll
        for (int c = 1; c <= 4; c++) {
            int d = 2 * cstart[c] - nT2;
            d = d < 0 ? -d : d;
            if (d < best) { best = d; sc = c; }
        }
        int cb = chalf ? sc : 0, ce = chalf ? 5 : sc;
        int t0 = cstart[cb] >> 6, tEnd = cstart[ce] >> 6;
        const unsigned short* Srow = &S[m][q * 8];
        const unsigned short* Vrow = &VtB[(size_t)(db + m) * NP + q * 8];
        bf16x8 a0 = {}, a1 = {}, b0 = {}, b1 = {};
        if (t0 < tEnd) {
            int jb = t0 * 64;
            a0 = *(const bf16x8*)&Srow[jb];  a1 = *(const bf16x8*)&Srow[jb + 32];
            b0 = *(const bf16x8*)&Vrow[jb];  b1 = *(const bf16x8*)&Vrow[jb + 32];
        }
        int tcur = t0;
        for (int c = cb; c < ce; c++) {
            int ct1 = cstart[c + 1] >> 6;
            f32x4 ae = {0.f, 0.f, 0.f, 0.f};
            f32x4 ao = {0.f, 0.f, 0.f, 0.f};
            while (tcur < ct1) {
                bf16x8 ca0 = a0, ca1 = a1, cb0 = b0, cb1 = b1;
                int tn = tcur + 1;
                if (tn < tEnd) {             // prefetch next tile (crosses class boundary)
                    int jb = tn * 64;
                    a0 = *(const bf16x8*)&Srow[jb];  a1 = *(const bf16x8*)&Srow[jb + 32];
                    b0 = *(const bf16x8*)&Vrow[jb];  b1 = *(const bf16x8*)&Vrow[jb + 32];
                }
                ae = __builtin_amdgcn_mfma_f32_16x16x32_bf16(ca0, cb0, ae, 0, 0, 0);
                ao = __builtin_amdgcn_mfma_f32_16x16x32_bf16(ca1, cb1, ao, 0, 0, 0);
                tcur++;
            }
#pragma unroll
            for (int g = 0; g < 4; g++)
                u[c][q * 4 + g][db + m] = f2bf(ae[g] + ao[g]);
        }
    }
    __syncthreads();   // S dead from here; pbuf region reusable

    // ---- phase 4: out = (sum_c u[c] . W2m[cls(r,c)]) ; wave = (kw, c-half); pbuf combine
    {
        int kw = wave & 3, p = wave >> 2;
        int cb = p ? 3 : 0, ce = p ? 5 : 3;
        f32x4 acc = {0.f, 0.f, 0.f, 0.f};
        for (int c = cb; c < ce; c++) {
            int cls = clsOf(r, c);
            const unsigned short* ua = &u[c][m][q * 8];
            bf16x8 a0 = *(const bf16x8*)ua;
            bf16x8 a1 = *(const bf16x8*)(ua + 32);
            const unsigned short* wb = W2bt + (((size_t)cls * NH + h) << 12)
                                     + (size_t)(kw * 16 + m) * 64 + q * 8;
            bf16x8 b0 = *(const bf16x8*)wb;
            bf16x8 b1 = *(const bf16x8*)(wb + 32);
            acc = __builtin_amdgcn_mfma_f32_16x16x32_bf16(a0, b0, acc, 0, 0, 0);
            acc = __builtin_amdgcn_mfma_f32_16x16x32_bf16(a1, b1, acc, 0, 0, 0);
        }
#pragma unroll
        for (int g = 0; g < 4; g++)
            pbuf[p][q * 4 + g][kw * 16 + m] = acc[g];
    }
    __syncthreads();

    // ---- epilogue: combine halves, normalize, store
    for (int idx = tid; idx < 16 * 64; idx += 512) {
        int i = idx >> 6, k = idx & 63;
        int tok = toki[i];
        if (tok >= 0) {
            float s = wsum[0][i] + wsum[1][i] + wsum[2][i] + wsum[3][i]
                    + wsum[4][i] + wsum[5][i] + wsum[6][i] + wsum[7][i];
            float v = pbuf[0][i][k] + pbuf[1][i][k];
            out[((size_t)b * NN + tok) * (NH * DKK) + h * DKK + k] = v / s;
        }
    }
}

// ---------------------------------------------------------------- launch
extern "C" void kernel_launch(void* const* d_in, const int* in_sizes, int n_in,
                              void* d_out, int out_size, void* d_ws, size_t ws_size,
                              hipStream_t stream)
{
    const float* qr  = (const float*)d_in[0];
    const float* kr  = (const float*)d_in[1];
    const float* vr  = (const float*)d_in[2];
    const void* bsr  = d_in[3];
    const void* mkr  = d_in[4];
    const float* lr  = (const float*)d_in[5];
    const float* w1r = (const float*)d_in[6];
    const float* a1r = (const float*)d_in[7];
    const float* w2r = (const float*)d_in[8];
    const float* a2r = (const float*)d_in[9];
    float* out = (float*)d_out;

    char* w = (char*)d_ws;
    int* maskI    = (int*)w;
    int* perm     = maskI + BQ * NN;
    int* rowc     = perm + BQ * NP;
    int* startPad = rowc + BQ * NP;
    int* maskP    = startPad + 12;
    unsigned short* W1bt = (unsigned short*)(w + 65536);
    unsigned short* W2bt = W1bt + (size_t)NCLS * NH * 4096;
    unsigned short* Qb   = (unsigned short*)(w + 2359296);
    unsigned short* Kb   = Qb + (size_t)BQ * NH * NP * 64;
    unsigned short* Vt   = Kb + (size_t)BQ * NH * NP * 64;           // [b][h][d][ip]
    unsigned short* Lt   = (unsigned short*)(w + 10616832);
    unsigned short* Xc   = (unsigned short*)(w + 26345472);          // total ~32.6 MB

    hipLaunchKernelGGL(k_prep, dim3(960 + 96 + 1), dim3(256), 0, stream,
                       lr, Lt, qr, kr, vr, Xc,
                       bsr, mkr, maskI, perm, rowc, startPad, maskP);
    hipLaunchKernelGGL(k_proj, dim3(960 + 2 * NCLS * NH), dim3(256), 0, stream,
                       Xc, Lt, perm, rowc, startPad, Qb, Kb, Vt,
                       w1r, w2r, a1r, a2r, W1bt, W2bt);
    hipLaunchKernelGGL(k_attn, dim3(8 * 2 * 80), dim3(512), 0, stream,
                       Qb, Kb, Vt, W1bt, W2bt, perm, rowc, startPad, maskI, maskP, out);
}

// Round 7
// 181.201 us; speedup vs baseline: 1.1589x; 1.0269x over previous
//
#include <hip/hip_runtime.h>
#include <hip/hip_bf16.h>
#include <math.h>

#define BQ   2      // batch
#define NN   1024   // seq len
#define DMD  512    // d_model
#define NH   8      // heads
#define DKK  64     // head dim
#define NSEL 5      // NB+1 block values (0..4)
#define NCLS 17     // block-pair classes
#define NP   1280   // padded per-batch capacity: nTot = sum(ceil(c_i/64)*64) <= 1339 and %64==0 -> <=1280
#define NPT  20     // NP/64 tiles
#define MAXT 3      // max key-tiles per wave in k_attn (ceil(20/8))
#define SSp  1284   // S row stride (shorts): 2568B = 642 words == 2 mod 32 banks, conflict-free shift
#define QLS  68     // qloc/u row stride (shorts)

typedef __attribute__((ext_vector_type(8))) short bf16x8;
typedef __attribute__((ext_vector_type(8))) unsigned short u16x8;
typedef __attribute__((ext_vector_type(4))) float f32x4;

__device__ __forceinline__ int clsOf(int r, int c) { return (r == 0 || c == 0) ? 0 : ((r - 1) * 4 + c); }

__device__ __forceinline__ unsigned short f2bf(float x) {
    __hip_bfloat16 h = __float2bfloat16(x);
    return *reinterpret_cast<unsigned short*>(&h);
}

// ---------------------------------------------------------------- prep: lin cast (960) + qkv cast (96) + setup (1)
__global__ __launch_bounds__(256) void k_prep(
    const float* __restrict__ lr, unsigned short* __restrict__ Lt,
    const float* __restrict__ qr, const float* __restrict__ kr, const float* __restrict__ vr,
    unsigned short* __restrict__ Xc,
    const void* __restrict__ b_seq_r, const void* __restrict__ mask_r,
    int* __restrict__ maskI, int* __restrict__ perm, int* __restrict__ rowc,
    int* __restrict__ startPad, int* __restrict__ maskP)
{
    __shared__ float Tf[64][68];
    __shared__ int det[5];
    __shared__ int cnts[BQ][NSEL];
    __shared__ int offs[BQ][NSEL];
    __shared__ int sstart[BQ][NSEL + 1];
    int bx = blockIdx.x;
    int tid = threadIdx.x;
    if (bx < 960) {
        // cast+transpose lin[ts][k][n] -> Lt[ts][n][k] bf16
        int ts = bx >> 6, rem = bx & 63;
        int kt = rem >> 3, nt = rem & 7;
        const float* src = lr + (size_t)ts * DMD * 512;
        unsigned short* dst = Lt + (size_t)ts * DMD * 512;
        int r = tid >> 2, c4 = tid & 3;
#pragma unroll
        for (int i = 0; i < 4; i++) {
            float4 v = *(const float4*)&src[(size_t)(kt * 64 + r) * 512 + nt * 64 + c4 * 16 + i * 4];
            *(float4*)&Tf[r][c4 * 16 + i * 4] = v;
        }
        __syncthreads();
        unsigned short tmp[16];
#pragma unroll
        for (int i = 0; i < 16; i++) tmp[i] = f2bf(Tf[c4 * 16 + i][r]);
        u16x8 o0, o1;
#pragma unroll
        for (int i = 0; i < 8; i++) { o0[i] = tmp[i]; o1[i] = tmp[8 + i]; }
        unsigned short* dp = &dst[(size_t)(nt * 64 + r) * 512 + kt * 64 + c4 * 16];
        *(u16x8*)&dp[0] = o0;
        *(u16x8*)&dp[8] = o1;
    } else if (bx < 960 + 96) {
        // cast q/k/v -> Xc bf16 [t][b][n][512]
        int bid = bx - 960;                     // 0..95
        int t = bid / 32, rem = bid % 32;
        int b = rem / 16, rg = rem % 16;
        int row = tid >> 2, part = tid & 3;
        const float* X = (t == 0) ? qr : ((t == 1) ? kr : vr);
        const float* src = X + ((size_t)b * NN + rg * 64 + row) * DMD + part * 128;
        unsigned short* dst = Xc + (((size_t)t * BQ + b) * NN + rg * 64 + row) * DMD + part * 128;
#pragma unroll
        for (int i = 0; i < 128; i += 8) {
            float4 v0 = *(const float4*)&src[i];
            float4 v1 = *(const float4*)&src[i + 4];
            u16x8 o;
            o[0] = f2bf(v0.x); o[1] = f2bf(v0.y); o[2] = f2bf(v0.z); o[3] = f2bf(v0.w);
            o[4] = f2bf(v1.x); o[5] = f2bf(v1.y); o[6] = f2bf(v1.z); o[7] = f2bf(v1.w);
            *(u16x8*)&dst[i] = o;
        }
    } else {
        // ---- setup (single block): dtype detect, bucketize, perm, masks
        if (tid < 5) det[tid] = 0;
        if (tid < BQ * NSEL) { cnts[tid / NSEL][tid % NSEL] = 0; offs[tid / NSEL][tid % NSEL] = 0; }
        __syncthreads();
        const int* b32 = (const int*)b_seq_r;
        const unsigned char* mb = (const unsigned char*)mask_r;
        const int* m32 = (const int*)mask_r;
        if (tid < 64) {
            if (b32[2 * tid + 1] != 0) atomicOr(&det[0], 1);
            if (b32[2 * tid] != 0)     atomicOr(&det[1], 1);
            if (m32[2 * tid + 1] != 0) atomicOr(&det[3], 1);
            if (m32[2 * tid] != 0)     atomicOr(&det[4], 1);
        }
        if ((tid & 3) != 0 && mb[tid] != 0) atomicOr(&det[2], 1);
        __syncthreads();
        int bsI64 = (det[0] == 0 && det[1] != 0);
        int mk = det[2] ? 1 : ((det[3] == 0 && det[4] != 0) ? 2 : 0);

        for (int g = tid; g < BQ * NN; g += 256) {
            int m = (mk == 1) ? (mb[g] != 0) : ((mk == 2) ? (m32[2 * g] != 0) : (m32[g] != 0));
            maskI[g] = m;
            int bs = bsI64 ? b32[2 * g] : b32[g];
            bs = bs < 0 ? 0 : (bs > 4 ? 4 : bs);
            atomicAdd(&cnts[g / NN][bs], 1);
        }
        __syncthreads();
        if (tid == 0) {
            for (int b = 0; b < BQ; b++) {
                int acc = 0;
                for (int c = 0; c < NSEL; c++) {
                    sstart[b][c] = acc;
                    acc += ((cnts[b][c] + 63) / 64) * 64;
                }
                sstart[b][NSEL] = acc;
                for (int c = 0; c <= NSEL; c++) startPad[b * (NSEL + 1) + c] = sstart[b][c];
            }
        }
        __syncthreads();
        for (int g = tid; g < BQ * NP; g += 256) {
            perm[g] = -1;
            int b = g / NP, sslot = g % NP;
            int c = 0;
            for (int cc = 1; cc < NSEL; cc++) if (sslot >= sstart[b][cc]) c = cc;
            rowc[g] = c;
        }
        __syncthreads();
        for (int g = tid; g < BQ * NN; g += 256) {
            int b = g / NN, n = g % NN;
            int bs = bsI64 ? b32[2 * g] : b32[g];
            bs = bs < 0 ? 0 : (bs > 4 ? 4 : bs);
            int pos = sstart[b][bs] + atomicAdd(&offs[b][bs], 1);
            perm[b * NP + pos] = n;
        }
        __syncthreads();
        for (int g = tid; g < BQ * NP; g += 256) {
            int tok = perm[g];
            maskP[g] = (tok < 0) ? 2 : maskI[(g / NP) * NN + tok];
        }
    }
}

// ---------------------------------------------------------------- QKV projection (960 blocks) + wmix (272 blocks)
__global__ __launch_bounds__(256) void k_proj(
    const unsigned short* __restrict__ Xc,
    const unsigned short* __restrict__ Lt,
    const int* __restrict__ perm, const int* __restrict__ rowc, const int* __restrict__ startPad,
    unsigned short* __restrict__ Qb, unsigned short* __restrict__ Kb,
    unsigned short* __restrict__ Vt,
    const float* __restrict__ W1, const float* __restrict__ W2,
    const float* __restrict__ al1, const float* __restrict__ al2,
    unsigned short* __restrict__ W1bt, unsigned short* __restrict__ W2bt)
{
    __shared__ __align__(16) unsigned short Xb[64][72];
    __shared__ __align__(16) unsigned short Lb[64][72];
    __shared__ int toks[64];

    int bid = blockIdx.x;
    int tid = threadIdx.x;
    if (bid >= 960) {
        // ---- wmix: W1m/W2m mixtures, transposed bf16
        int bid2 = bid - 960;
        int w = bid2 / (NCLS * NH);
        int rem = bid2 % (NCLS * NH);
        int c = rem / NH, h = rem % NH;
        const float* W = w ? W2 : W1;
        const float* a = w ? al2 : al1;
        unsigned short* outp = (w ? W2bt : W1bt) + (((size_t)c * NH + h) << 12);
        float vals[4], mx = -1e30f;
#pragma unroll
        for (int bb = 0; bb < 4; bb++) { vals[bb] = a[(c * 4 + bb) * NH + h]; mx = fmaxf(mx, vals[bb]); }
        float ssum = 0.f;
#pragma unroll
        for (int bb = 0; bb < 4; bb++) { vals[bb] = __expf(vals[bb] - mx); ssum += vals[bb]; }
        float inv = 1.0f / ssum;
        float s0 = vals[0] * inv, s1 = vals[1] * inv, s2 = vals[2] * inv, s3 = vals[3] * inv;
        const float* p0 = W + (size_t)(0 * NH + h) * 4096;
        const float* p1 = W + (size_t)(1 * NH + h) * 4096;
        const float* p2 = W + (size_t)(2 * NH + h) * 4096;
        const float* p3 = W + (size_t)(3 * NH + h) * 4096;
        for (int e = tid; e < 4096; e += 256) {
            float v = s0 * p0[e] + s1 * p1[e] + s2 * p2[e] + s3 * p3[e];
            int mm = e >> 6, nn = e & 63;
            outp[nn * 64 + mm] = f2bf(v);     // transposed store
        }
        return;
    }

    int xcd = bid & 7, local = bid >> 3;          // 0..119
    int t = local / 40, rem = local % 40;
    int ti = rem >> 1, half = rem & 1;
    int qtr = xcd & 3, b = xcd >> 2;

    int nTot = startPad[b * (NSEL + 1) + NSEL];
    if (ti * 64 >= nTot) return;
    int sel = rowc[b * NP + ti * 64];
    const unsigned short* XcT = Xc + ((size_t)t * BQ + b) * NN * DMD;
    const unsigned short* L = Lt + (size_t)(t * NSEL + sel) * DMD * 512;   // [n][k] bf16

    int wave = tid >> 6, lane = tid & 63;
    int m = lane & 15, q = lane >> 4;
    if (tid < 64) toks[tid] = perm[b * NP + ti * 64 + tid];
    __syncthreads();

    int xr = tid >> 2, xc0 = (tid & 3) * 16;
    int xtok = toks[xr];
    const unsigned short* xbase = (xtok >= 0) ? &XcT[(size_t)xtok * DMD] : (const unsigned short*)0;
    int lrow = tid >> 2, lc0 = (tid & 3) * 16;
    const unsigned short* lbase = &L[(size_t)(qtr * 128 + half * 64 + lrow) * 512 + lc0];

    u16x8 rx0 = {0, 0, 0, 0, 0, 0, 0, 0}, rx1 = {0, 0, 0, 0, 0, 0, 0, 0};
    u16x8 rl0, rl1;
    if (xbase) { rx0 = *(const u16x8*)&xbase[xc0]; rx1 = *(const u16x8*)&xbase[xc0 + 8]; }
    rl0 = *(const u16x8*)&lbase[0];
    rl1 = *(const u16x8*)&lbase[8];

    f32x4 acc[4];
#pragma unroll
    for (int mt = 0; mt < 4; mt++) acc[mt] = {0, 0, 0, 0};

    for (int kb = 0; kb < DMD; kb += 64) {
        *(u16x8*)&Xb[xr][xc0] = rx0;
        *(u16x8*)&Xb[xr][xc0 + 8] = rx1;
        *(u16x8*)&Lb[lrow][lc0] = rl0;
        *(u16x8*)&Lb[lrow][lc0 + 8] = rl1;
        __syncthreads();
        if (kb + 64 < DMD) {   // prefetch next slab (overlaps MFMAs)
            int nk = kb + 64;
            if (xbase) { rx0 = *(const u16x8*)&xbase[nk + xc0]; rx1 = *(const u16x8*)&xbase[nk + xc0 + 8]; }
            rl0 = *(const u16x8*)&lbase[nk];
            rl1 = *(const u16x8*)&lbase[nk + 8];
        }
#pragma unroll
        for (int kc = 0; kc < 64; kc += 32) {
            bf16x8 bfrag = *(const bf16x8*)&Lb[wave * 16 + m][kc + q * 8];
#pragma unroll
            for (int mt = 0; mt < 4; mt++) {
                bf16x8 a = *(const bf16x8*)&Xb[mt * 16 + m][kc + q * 8];
                acc[mt] = __builtin_amdgcn_mfma_f32_16x16x32_bf16(a, bfrag, acc[mt], 0, 0, 0);
            }
        }
        __syncthreads();
    }

    if (t < 2) {
        unsigned short* O = (t == 0) ? Qb : Kb;
        int hk = qtr * 128 + half * 64 + wave * 16 + m;
        int h = hk >> 6, k0 = hk & 63;
#pragma unroll
        for (int mt = 0; mt < 4; mt++)
#pragma unroll
            for (int gg = 0; gg < 4; gg++) {
                int i = mt * 16 + q * 4 + gg;
                O[(((size_t)b * NH + h) * NP + ti * 64 + i) * 64 + k0] = f2bf(acc[mt][gg]);
            }
    } else {
        // transpose via Lb (dead), write Vt[b][h][d][ip] coalesced
#pragma unroll
        for (int mt = 0; mt < 4; mt++)
#pragma unroll
            for (int gg = 0; gg < 4; gg++)
                Lb[wave * 16 + m][mt * 16 + q * 4 + gg] = f2bf(acc[mt][gg]);
        __syncthreads();
        int hkl = tid >> 2, part = tid & 3;
        int hk = qtr * 128 + half * 64 + hkl;
        int h = hk >> 6, d = hk & 63;
        unsigned short* vp = Vt + (((size_t)b * NH + h) * DKK + d) * NP + ti * 64 + part * 16;
        *(u16x8*)&vp[0] = *(const u16x8*)&Lb[hkl][part * 16];
        *(u16x8*)&vp[8] = *(const u16x8*)&Lb[hkl][part * 16 + 8];
    }
}

// ---------------------------------------------------------------- fused attention: 512 threads, XCD-swizzled
// Round-2 base + three surgical phase-1/3 changes (resubmit of round 6 — infra failure, untested):
//  (a) 1-deep cross-slot K prefetch (half of next slot's K issued before this slot's MFMA burst)
//  (b) wave-uniform skip of invalid slots (tiles=17..20 of 24 slots)
//  (c) s_setprio(1) around phase-1/3 MFMA bursts (T5)
__global__ __launch_bounds__(512, 4) void k_attn(
    const unsigned short* __restrict__ Qb, const unsigned short* __restrict__ Kb,
    const unsigned short* __restrict__ Vt, const unsigned short* __restrict__ W1bt,
    const unsigned short* __restrict__ W2bt,
    const int* __restrict__ perm, const int* __restrict__ rowc, const int* __restrict__ startPad,
    const int* __restrict__ maskI, const int* __restrict__ maskP,
    float* __restrict__ out)
{
    int bid = blockIdx.x;
    int xcd = bid & 7, local = bid >> 3;          // 0..159
    int bh = xcd * 2 + (local >= 80 ? 1 : 0);
    int it = (local >= 80) ? (local - 80) : local;
    int b = bh >> 3, h = bh & 7;
    int nTot = startPad[b * (NSEL + 1) + NSEL];
    int i0 = it * 16;
    if (i0 >= nTot) return;
    int r = rowc[b * NP + i0];
    int tiles = nTot >> 6;

    // ---- LDS union (53224 B): S | u | wred | wsum | tilec | cstart | mrow | toki
    __shared__ __align__(16) char smem[16 * SSp * 2 + NSEL * 16 * QLS * 2 + 1024 + 4 * (NPT + 6 + 16 + 16)];
    unsigned short (*S)[SSp] = (unsigned short (*)[SSp])smem;                 // phases 2-3
    unsigned short (*qloc)[16][QLS] = (unsigned short (*)[16][QLS])smem;      // phases 0b-1 (aliases S)
    float (*pbuf)[16][64] = (float (*)[16][64])smem;                          // phase 4 (aliases S)
    unsigned short (*u)[16][QLS] = (unsigned short (*)[16][QLS])(smem + 16 * SSp * 2);
    char* tail = smem + 16 * SSp * 2 + NSEL * 16 * QLS * 2;
    float (*wred)[16] = (float (*)[16])tail;
    float (*wsum)[16] = (float (*)[16])(tail + 512);
    int* tilec = (int*)(tail + 1024);
    int* cstart = tilec + NPT;
    int* mrow = cstart + 6;
    int* toki = mrow + 16;

    int tid = threadIdx.x;
    int wave = tid >> 6, lane = tid & 63;
    int m = lane & 15, q = lane >> 4;

    const int* permB = perm + b * NP;
    const unsigned short* QbB = Qb + (size_t)bh * NP * 64;
    const unsigned short* KbB = Kb + (size_t)bh * NP * 64;
    const unsigned short* VtB = Vt + (size_t)bh * DKK * NP;      // [d][jp]
    const int* maskPB = maskP + b * NP;

    if (tid < NPT) tilec[tid] = rowc[b * NP + tid * 64];
    else if (tid >= 32 && tid < 38) cstart[tid - 32] = startPad[b * (NSEL + 1) + (tid - 32)];
    else if (tid >= 64 && tid < 80) {
        int rr = tid - 64;
        int tok = permB[i0 + rr];
        toki[rr] = tok;
        mrow[rr] = (tok >= 0) ? maskI[b * NN + tok] : 0;
    }

    // ---- phase 0b: qloc[c][i][n] = Q . W1m[cls(r,c)]; 8 waves = {c-half} x {n-subtile}
    {
        const unsigned short* qa = &QbB[(size_t)(i0 + m) * 64 + q * 8];
        bf16x8 a0 = *(const bf16x8*)qa;
        bf16x8 a1 = *(const bf16x8*)(qa + 32);
        int sub = wave & 3;
        int c0 = (wave >> 2) ? 3 : 0;
        int c1 = (wave >> 2) ? 5 : 3;
        for (int c = c0; c < c1; c++) {
            int cls = clsOf(r, c);
            const unsigned short* wb = W1bt + (((size_t)cls * NH + h) << 12)
                                     + (size_t)(sub * 16 + m) * 64 + q * 8;
            bf16x8 b0 = *(const bf16x8*)wb;
            bf16x8 b1 = *(const bf16x8*)(wb + 32);
            f32x4 acc = {0.f, 0.f, 0.f, 0.f};
            acc = __builtin_amdgcn_mfma_f32_16x16x32_bf16(a0, b0, acc, 0, 0, 0);
            acc = __builtin_amdgcn_mfma_f32_16x16x32_bf16(a1, b1, acc, 0, 0, 0);
#pragma unroll
            for (int g = 0; g < 4; g++)
                qloc[c][q * 4 + g][sub * 16 + m] = f2bf(acc[g]);
        }
    }
    __syncthreads();

    // ---- phase 1: scores in registers; 1-deep cross-slot K prefetch, invalid slots skipped
    float sarr[MAXT][4][4];
    float lmax[4] = {-INFINITY, -INFINITY, -INFINITY, -INFINITY};
    int mrow4[4];
#pragma unroll
    for (int g = 0; g < 4; g++) mrow4[g] = mrow[q * 4 + g];

    int nslots = 0;                                   // valid slots for this wave (wave-uniform)
    while (nslots < MAXT && wave + nslots * 8 < tiles) nslots++;

    bf16x8 kA[8], kB[4];
    int mjA[4];
    if (nslots > 0) {                                  // preload slot 0 fully
        int jb = wave * 64;
#pragma unroll
        for (int nb = 0; nb < 4; nb++) {
            int j = jb + nb * 16 + m;
            const unsigned short* kb = &KbB[(size_t)j * 64 + q * 8];
            kA[nb * 2]     = *(const bf16x8*)kb;
            kA[nb * 2 + 1] = *(const bf16x8*)(kb + 32);
            mjA[nb] = maskPB[j];
        }
    }
#pragma unroll
    for (int tt = 0; tt < MAXT; tt++) {
        if (tt < nslots) {
            int jt = wave + tt * 8;
            int c = tilec[jt];
            const unsigned short* qa = &qloc[c][m][q * 8];
            bf16x8 a0 = *(const bf16x8*)qa;
            bf16x8 a1 = *(const bf16x8*)(qa + 32);
            bool pf = (tt + 1 < nslots);
            int jbN = (wave + (tt + 1) * 8) * 64;
            if (pf) {                                  // issue half of next slot's K before MFMAs
#pragma unroll
                for (int nb = 0; nb < 2; nb++) {
                    int j = jbN + nb * 16 + m;
                    const unsigned short* kb = &KbB[(size_t)j * 64 + q * 8];
                    kB[nb * 2]     = *(const bf16x8*)kb;
                    kB[nb * 2 + 1] = *(const bf16x8*)(kb + 32);
                }
            }
            __builtin_amdgcn_s_setprio(1);
#pragma unroll
            for (int nb = 0; nb < 4; nb++) {
                f32x4 acc = {0.f, 0.f, 0.f, 0.f};
                acc = __builtin_amdgcn_mfma_f32_16x16x32_bf16(a0, kA[nb * 2], acc, 0, 0, 0);
                acc = __builtin_amdgcn_mfma_f32_16x16x32_bf16(a1, kA[nb * 2 + 1], acc, 0, 0, 0);
                int mj = mjA[nb];
#pragma unroll
                for (int g = 0; g < 4; g++) {
                    float sv;
                    if (mj == 2)             sv = -INFINITY;      // padding slot
                    else if (mrow4[g] && mj) sv = acc[g] * 0.125f;
                    else                     sv = -1e30f;         // reference's masked value
                    sarr[tt][nb][g] = sv;
                    lmax[g] = fmaxf(lmax[g], sv);
                }
            }
            __builtin_amdgcn_s_setprio(0);
            if (pf) {                                  // rotate prefetched half in, load rest
#pragma unroll
                for (int i = 0; i < 4; i++) kA[i] = kB[i];
#pragma unroll
                for (int nb = 2; nb < 4; nb++) {
                    int j = jbN + nb * 16 + m;
                    const unsigned short* kb = &KbB[(size_t)j * 64 + q * 8];
                    kA[nb * 2]     = *(const bf16x8*)kb;
                    kA[nb * 2 + 1] = *(const bf16x8*)(kb + 32);
                }
#pragma unroll
                for (int nb = 0; nb < 4; nb++) mjA[nb] = maskPB[jbN + nb * 16 + m];
            }
        } else {
#pragma unroll
            for (int nb = 0; nb < 4; nb++)
#pragma unroll
                for (int g = 0; g < 4; g++) sarr[tt][nb][g] = -INFINITY;
        }
    }
#pragma unroll
    for (int g = 0; g < 4; g++) {
        float v = lmax[g];
#pragma unroll
        for (int o = 1; o < 16; o <<= 1) v = fmaxf(v, __shfl_xor(v, o));
        lmax[g] = v;
    }
    if (m == 0) {
#pragma unroll
        for (int g = 0; g < 4; g++) wred[wave][q * 4 + g] = lmax[g];
    }
    __syncthreads();   // qloc dead from here

    // ---- phase 2: exp in regs, single P write into S, row sums (normalization deferred)
    float mx4[4], lsum[4] = {0.f, 0.f, 0.f, 0.f};
#pragma unroll
    for (int g = 0; g < 4; g++) {
        int i = q * 4 + g;
        float v = wred[0][i];
#pragma unroll
        for (int w2 = 1; w2 < 8; w2++) v = fmaxf(v, wred[w2][i]);
        mx4[g] = v;
    }
#pragma unroll
    for (int tt = 0; tt < MAXT; tt++) {
        int jt = wave + tt * 8;
        if (jt < tiles) {                              // wave-uniform skip (exp(-inf)=0 adds nothing)
            int jb = jt * 64;
#pragma unroll
            for (int nb = 0; nb < 4; nb++) {
                int j = jb + nb * 16 + m;
#pragma unroll
                for (int g = 0; g < 4; g++) {
                    float p = __expf(sarr[tt][nb][g] - mx4[g]);   // -inf -> 0
                    lsum[g] += p;
                    S[q * 4 + g][j] = f2bf(p);
                }
            }
        }
    }
#pragma unroll
    for (int g = 0; g < 4; g++) {
        float v = lsum[g];
#pragma unroll
        for (int o = 1; o < 16; o <<= 1) v += __shfl_xor(v, o);
        lsum[g] = v;
    }
    if (m == 0) {
#pragma unroll
        for (int g = 0; g < 4; g++) wsum[wave][q * 4 + g] = lsum[g];
    }
    __syncthreads();

    // ---- phase 3: per-class PV into u; wave = (kw, c-half)
    //      dynamic split point sc balances tile counts between wave halves;
    //      1-deep register prefetch of S-row + V-row carried across class boundaries.
    {
        int kw = wave & 3, chalf = wave >> 2;
        int db = kw * 16;
        int nT2 = cstart[5];
        int sc = 1, best = 0x7fffffff;
#pragma unroll
        for (int c = 1; c <= 4; c++) {
            int d = 2 * cstart[c] - nT2;
            d = d < 0 ? -d : d;
            if (d < best) { best = d; sc = c; }
        }
        int cb = chalf ? sc : 0, ce = chalf ? 5 : sc;
        int t0 = cstart[cb] >> 6, tEnd = cstart[ce] >> 6;
        const unsigned short* Srow = &S[m][q * 8];
        const unsigned short* Vrow = &VtB[(size_t)(db + m) * NP + q * 8];
        bf16x8 a0 = {}, a1 = {}, b0 = {}, b1 = {};
        if (t0 < tEnd) {
            int jb = t0 * 64;
            a0 = *(const bf16x8*)&Srow[jb];  a1 = *(const bf16x8*)&Srow[jb + 32];
            b0 = *(const bf16x8*)&Vrow[jb];  b1 = *(const bf16x8*)&Vrow[jb + 32];
        }
        int tcur = t0;
        for (int c = cb; c < ce; c++) {
            int ct1 = cstart[c + 1] >> 6;
            f32x4 ae = {0.f, 0.f, 0.f, 0.f};
            f32x4 ao = {0.f, 0.f, 0.f, 0.f};
            while (tcur < ct1) {
                bf16x8 ca0 = a0, ca1 = a1, cb0 = b0, cb1 = b1;
                int tn = tcur + 1;
                if (tn < tEnd) {             // prefetch next tile (crosses class boundary)
                    int jb = tn * 64;
                    a0 = *(const bf16x8*)&Srow[jb];  a1 = *(const bf16x8*)&Srow[jb + 32];
                    b0 = *(const bf16x8*)&Vrow[jb];  b1 = *(const bf16x8*)&Vrow[jb + 32];
                }
                __builtin_amdgcn_s_setprio(1);
                ae = __builtin_amdgcn_mfma_f32_16x16x32_bf16(ca0, cb0, ae, 0, 0, 0);
                ao = __builtin_amdgcn_mfma_f32_16x16x32_bf16(ca1, cb1, ao, 0, 0, 0);
                __builtin_amdgcn_s_setprio(0);
                tcur++;
            }
#pragma unroll
            for (int g = 0; g < 4; g++)
                u[c][q * 4 + g][db + m] = f2bf(ae[g] + ao[g]);
        }
    }
    __syncthreads();   // S dead from here; pbuf region reusable

    // ---- phase 4: out = (sum_c u[c] . W2m[cls(r,c)]) ; wave = (kw, c-half); pbuf combine
    {
        int kw = wave & 3, p = wave >> 2;
        int cb = p ? 3 : 0, ce = p ? 5 : 3;
        f32x4 acc = {0.f, 0.f, 0.f, 0.f};
        for (int c = cb; c < ce; c++) {
            int cls = clsOf(r, c);
            const unsigned short* ua = &u[c][m][q * 8];
            bf16x8 a0 = *(const bf16x8*)ua;
            bf16x8 a1 = *(const bf16x8*)(ua + 32);
            const unsigned short* wb = W2bt + (((size_t)cls * NH + h) << 12)
                                     + (size_t)(kw * 16 + m) * 64 + q * 8;
            bf16x8 b0 = *(const bf16x8*)wb;
            bf16x8 b1 = *(const bf16x8*)(wb + 32);
            acc = __builtin_amdgcn_mfma_f32_16x16x32_bf16(a0, b0, acc, 0, 0, 0);
            acc = __builtin_amdgcn_mfma_f32_16x16x32_bf16(a1, b1, acc, 0, 0, 0);
        }
#pragma unroll
        for (int g = 0; g < 4; g++)
            pbuf[p][q * 4 + g][kw * 16 + m] = acc[g];
    }
    __syncthreads();

    // ---- epilogue: combine halves, normalize, store
    for (int idx = tid; idx < 16 * 64; idx += 512) {
        int i = idx >> 6, k = idx & 63;
        int tok = toki[i];
        if (tok >= 0) {
            float s = wsum[0][i] + wsum[1][i] + wsum[2][i] + wsum[3][i]
                    + wsum[4][i] + wsum[5][i] + wsum[6][i] + wsum[7][i];
            float v = pbuf[0][i][k] + pbuf[1][i][k];
            out[((size_t)b * NN + tok) * (NH * DKK) + h * DKK + k] = v / s;
        }
    }
}

// ---------------------------------------------------------------- launch
extern "C" void kernel_launch(void* const* d_in, const int* in_sizes, int n_in,
                              void* d_out, int out_size, void* d_ws, size_t ws_size,
                              hipStream_t stream)
{
    const float* qr  = (const float*)d_in[0];
    const float* kr  = (const float*)d_in[1];
    const float* vr  = (const float*)d_in[2];
    const void* bsr  = d_in[3];
    const void* mkr  = d_in[4];
    const float* lr  = (const float*)d_in[5];
    const float* w1r = (const float*)d_in[6];
    const float* a1r = (const float*)d_in[7];
    const float* w2r = (const float*)d_in[8];
    const float* a2r = (const float*)d_in[9];
    float* out = (float*)d_out;

    char* w = (char*)d_ws;
    int* maskI    = (int*)w;
    int* perm     = maskI + BQ * NN;
    int* rowc     = perm + BQ * NP;
    int* startPad = rowc + BQ * NP;
    int* maskP    = startPad + 12;
    unsigned short* W1bt = (unsigned short*)(w + 65536);
    unsigned short* W2bt = W1bt + (size_t)NCLS * NH * 4096;
    unsigned short* Qb   = (unsigned short*)(w + 2359296);
    unsigned short* Kb   = Qb + (size_t)BQ * NH * NP * 64;
    unsigned short* Vt   = Kb + (size_t)BQ * NH * NP * 64;           // [b][h][d][ip]
    unsigned short* Lt   = (unsigned short*)(w + 10616832);
    unsigned short* Xc   = (unsigned short*)(w + 26345472);          // total ~32.6 MB

    hipLaunchKernelGGL(k_prep, dim3(960 + 96 + 1), dim3(256), 0, stream,
                       lr, Lt, qr, kr, vr, Xc,
                       bsr, mkr, maskI, perm, rowc, startPad, maskP);
    hipLaunchKernelGGL(k_proj, dim3(960 + 2 * NCLS * NH), dim3(256), 0, stream,
                       Xc, Lt, perm, rowc, startPad, Qb, Kb, Vt,
                       w1r, w2r, a1r, a2r, W1bt, W2bt);
    hipLaunchKernelGGL(k_attn, dim3(8 * 2 * 80), dim3(512), 0, stream,
                       Qb, Kb, Vt, W1bt, W2bt, perm, rowc, startPad, maskI, maskP, out);
}